// Round 1
// baseline (486.371 us; speedup 1.0000x reference)
//
#include <hip/hip_runtime.h>
#include <hip/hip_bf16.h>

#define S_   4
#define N_   16384
#define K_   128
#define PPB  32        // pairs per block
#define NT   256       // threads per block (4 waves)
#define FSTR 260       // feat row stride (2*K + 4 pad), %4==0 for float4
#define O0STR 132      // o0 row stride (K + 4 pad)
#define O1STR 68       // o1 row stride (K/2 + 4 pad)

__device__ __forceinline__ float lrelu(float x) { return x > 0.f ? x : 0.01f * x; }

// Embedding for one side of one pair. One full wave cooperates; lane handles
// k = 2*lane, 2*lane+1. Writes 0.5*(e5+e8) (K floats) to dst (LDS).
__device__ __forceinline__ void embed_side(
    const float* __restrict__ Z, int idx,
    const float* __restrict__ Wc1, float bc1v,
    const float* __restrict__ Wc2, const float* __restrict__ bc2,
    float sw0, float sw1, float sw2, float sw3,
    int lane, float* dst)
{
    const int k0 = 2 * lane;
    const float* base = Z + (size_t)idx * K_ + k0;
    // coalesced: wave reads one contiguous 512B row per s
    float2 z0 = *(const float2*)(base + (size_t)0 * N_ * K_);
    float2 z1 = *(const float2*)(base + (size_t)1 * N_ * K_);
    float2 z2 = *(const float2*)(base + (size_t)2 * N_ * K_);
    float2 z3 = *(const float2*)(base + (size_t)3 * N_ * K_);

    float zs0 = z0.x + z1.x + z2.x + z3.x;
    float zs1 = z0.y + z1.y + z2.y + z3.y;

    // dot(Zcat, Wc1): Zcat[s*K+k]
    float2 w0 = *(const float2*)(Wc1 + 0 * K_ + k0);
    float2 w1 = *(const float2*)(Wc1 + 1 * K_ + k0);
    float2 w2 = *(const float2*)(Wc1 + 2 * K_ + k0);
    float2 w3 = *(const float2*)(Wc1 + 3 * K_ + k0);
    float dp = z0.x * w0.x + z0.y * w0.y + z1.x * w1.x + z1.y * w1.y
             + z2.x * w2.x + z2.y * w2.y + z3.x * w3.x + z3.y * w3.y;
#pragma unroll
    for (int off = 32; off >= 1; off >>= 1) dp += __shfl_xor(dp, off, 64);

    float a = dp + bc1v;
    a = lrelu(a);

    // attention logits over K, softmax
    float2 c2 = *(const float2*)(Wc2 + k0);
    float2 cb = *(const float2*)(bc2 + k0);
    float l0 = fmaf(a, c2.x, cb.x);
    float l1 = fmaf(a, c2.y, cb.y);
    float m = fmaxf(l0, l1);
#pragma unroll
    for (int off = 32; off >= 1; off >>= 1) m = fmaxf(m, __shfl_xor(m, off, 64));
    float e0 = __expf(l0 - m), e1 = __expf(l1 - m);
    float s = e0 + e1;
#pragma unroll
    for (int off = 32; off >= 1; off >>= 1) s += __shfl_xor(s, off, 64);
    float inv = 1.f / s;

    // e8: view-softmax-weighted sum over s
    float e8a = sw0 * z0.x + sw1 * z1.x + sw2 * z2.x + sw3 * z3.x;
    float e8b = sw0 * z0.y + sw1 * z1.y + sw2 * z2.y + sw3 * z3.y;

    float emb0 = 0.5f * (zs0 * (e0 * inv) + e8a);
    float emb1 = 0.5f * (zs1 * (e1 * inv) + e8b);
    *(float2*)(dst + k0) = make_float2(emb0, emb1);
}

__global__ __launch_bounds__(NT)
void mf_fused(const float* __restrict__ X, const float* __restrict__ Y,
              const float* __restrict__ x_att, const float* __restrict__ y_att,
              const float* __restrict__ WcX1, const float* __restrict__ bcX1,
              const float* __restrict__ WcX2, const float* __restrict__ bcX2,
              const float* __restrict__ WcY1, const float* __restrict__ bcY1,
              const float* __restrict__ WcY2, const float* __restrict__ bcY2,
              const float* __restrict__ W0, const float* __restrict__ b0,
              const float* __restrict__ W1, const float* __restrict__ b1,
              const float* __restrict__ W2, const float* __restrict__ b2,
              const int* __restrict__ idx0, const int* __restrict__ idx1,
              float* __restrict__ out, int Btot)
{
    // LDS pool, aliased across phases:
    //   feat [PPB][FSTR]      offset 0                (phase 1 -> layer0 reads)
    //   o0   [PPB][O0STR]     offset 0                (after layer0, feat dead)
    //   o1   [PPB][O1STR]     offset PPB*O0STR        (disjoint from o0)
    __shared__ float pool[PPB * FSTR];
    float* feat = pool;

    const int tid  = threadIdx.x;
    const int lane = tid & 63;
    const int wave = tid >> 6;

    // view-softmax weights for both sides (computed redundantly per thread; cheap)
    float swx0, swx1, swx2, swx3, swy0, swy1, swy2, swy3;
    {
        float a0 = x_att[0], a1 = x_att[1], a2 = x_att[2], a3 = x_att[3];
        float m = fmaxf(fmaxf(a0, a1), fmaxf(a2, a3));
        float e0 = __expf(a0 - m), e1 = __expf(a1 - m), e2 = __expf(a2 - m), e3 = __expf(a3 - m);
        float inv = 1.f / (e0 + e1 + e2 + e3);
        swx0 = e0 * inv; swx1 = e1 * inv; swx2 = e2 * inv; swx3 = e3 * inv;
        float b0v = y_att[0], b1v = y_att[1], b2v = y_att[2], b3v = y_att[3];
        float my = fmaxf(fmaxf(b0v, b1v), fmaxf(b2v, b3v));
        float f0 = __expf(b0v - my), f1 = __expf(b1v - my), f2 = __expf(b2v - my), f3 = __expf(b3v - my);
        float invy = 1.f / (f0 + f1 + f2 + f3);
        swy0 = f0 * invy; swy1 = f1 * invy; swy2 = f2 * invy; swy3 = f3 * invy;
    }

    const float bcX1v = bcX1[0];
    const float bcY1v = bcY1[0];
    const long pair_base = (long)blockIdx.x * PPB;

    // ---------------- phase 1: embeddings (wave-per-pair) ----------------
    for (int pp = 0; pp < PPB / 4; ++pp) {
        const int p_local = wave * (PPB / 4) + pp;
        const long pair = pair_base + p_local;
        if (pair < Btot) {
            embed_side(X, idx0[pair], WcX1, bcX1v, WcX2, bcX2,
                       swx0, swx1, swx2, swx3, lane, feat + p_local * FSTR);
            embed_side(Y, idx1[pair], WcY1, bcY1v, WcY2, bcY2,
                       swy0, swy1, swy2, swy3, lane, feat + p_local * FSTR + K_);
        }
    }
    __syncthreads();

    // ---------------- layer 0: [PPB,256] @ W0[256,128], lrelu ----------------
    const int jg = tid & 15;   // output cols j = jg*8 .. jg*8+7
    const int pg = tid >> 4;   // pairs pg*2, pg*2+1
    float acc[2][8];
#pragma unroll
    for (int p = 0; p < 2; ++p)
#pragma unroll
        for (int j = 0; j < 8; ++j) acc[p][j] = 0.f;

    const float* frow0 = feat + (pg * 2 + 0) * FSTR;
    const float* frow1 = feat + (pg * 2 + 1) * FSTR;
    for (int i = 0; i < 2 * K_; i += 4) {
        float fav[4], fbv[4];
        *(float4*)fav = *(const float4*)(frow0 + i);
        *(float4*)fbv = *(const float4*)(frow1 + i);
#pragma unroll
        for (int u = 0; u < 4; ++u) {
            float wv[8];
            *(float4*)(wv)     = *(const float4*)(W0 + (i + u) * K_ + jg * 8);
            *(float4*)(wv + 4) = *(const float4*)(W0 + (i + u) * K_ + jg * 8 + 4);
#pragma unroll
            for (int j = 0; j < 8; ++j) {
                acc[0][j] = fmaf(fav[u], wv[j], acc[0][j]);
                acc[1][j] = fmaf(fbv[u], wv[j], acc[1][j]);
            }
        }
    }
    __syncthreads();   // all feat reads done; pool reusable as o0

    float* o0 = pool;  // [PPB][O0STR]
    {
        float bv[8];
        *(float4*)bv       = *(const float4*)(b0 + jg * 8);
        *(float4*)(bv + 4) = *(const float4*)(b0 + jg * 8 + 4);
#pragma unroll
        for (int p = 0; p < 2; ++p) {
            float v[8];
#pragma unroll
            for (int j = 0; j < 8; ++j) v[j] = lrelu(acc[p][j] + bv[j]);
            *(float4*)(o0 + (pg * 2 + p) * O0STR + jg * 8)     = *(float4*)v;
            *(float4*)(o0 + (pg * 2 + p) * O0STR + jg * 8 + 4) = *(float4*)(v + 4);
        }
    }
    __syncthreads();

    // ---------------- layer 1: [PPB,128] @ W1[128,64], lrelu ----------------
    float acc1[2][4];
#pragma unroll
    for (int p = 0; p < 2; ++p)
#pragma unroll
        for (int j = 0; j < 4; ++j) acc1[p][j] = 0.f;

    const float* r0 = o0 + (pg * 2 + 0) * O0STR;
    const float* r1 = o0 + (pg * 2 + 1) * O0STR;
    for (int i = 0; i < K_; i += 4) {
        float fav[4], fbv[4];
        *(float4*)fav = *(const float4*)(r0 + i);
        *(float4*)fbv = *(const float4*)(r1 + i);
#pragma unroll
        for (int u = 0; u < 4; ++u) {
            float wv[4];
            *(float4*)wv = *(const float4*)(W1 + (i + u) * (K_ / 2) + jg * 4);
#pragma unroll
            for (int j = 0; j < 4; ++j) {
                acc1[0][j] = fmaf(fav[u], wv[j], acc1[0][j]);
                acc1[1][j] = fmaf(fbv[u], wv[j], acc1[1][j]);
            }
        }
    }

    float* o1 = pool + PPB * O0STR;  // [PPB][O1STR], disjoint from o0
    {
        float bv[4];
        *(float4*)bv = *(const float4*)(b1 + jg * 4);
#pragma unroll
        for (int p = 0; p < 2; ++p) {
            float v[4];
#pragma unroll
            for (int j = 0; j < 4; ++j) v[j] = lrelu(acc1[p][j] + bv[j]);
            *(float4*)(o1 + (pg * 2 + p) * O1STR + jg * 4) = *(float4*)v;
        }
    }
    __syncthreads();

    // ---------------- layer 2: [PPB,64] @ W2[64,1] + sigmoid ----------------
    {
        const int p    = tid >> 3;  // 0..31
        const int part = tid & 7;   // i-range part*8 .. part*8+7
        const float* r = o1 + p * O1STR + part * 8;
        float rv[8], wv[8];
        *(float4*)rv       = *(const float4*)(r);
        *(float4*)(rv + 4) = *(const float4*)(r + 4);
        *(float4*)wv       = *(const float4*)(W2 + part * 8);
        *(float4*)(wv + 4) = *(const float4*)(W2 + part * 8 + 4);
        float d = 0.f;
#pragma unroll
        for (int j = 0; j < 8; ++j) d = fmaf(rv[j], wv[j], d);
        d += __shfl_xor(d, 1, 64);
        d += __shfl_xor(d, 2, 64);
        d += __shfl_xor(d, 4, 64);
        if (part == 0) {
            const long pair = pair_base + p;
            if (pair < Btot) {
                float pred = d + b2[0];
                out[pair] = 1.f / (1.f + __expf(-pred));
            }
        }
    }
}

extern "C" void kernel_launch(void* const* d_in, const int* in_sizes, int n_in,
                              void* d_out, int out_size, void* d_ws, size_t ws_size,
                              hipStream_t stream) {
    const float* X    = (const float*)d_in[0];
    const float* Y    = (const float*)d_in[1];
    const float* xatt = (const float*)d_in[2];
    const float* yatt = (const float*)d_in[3];
    const float* WcX1 = (const float*)d_in[4];
    const float* bcX1 = (const float*)d_in[5];
    const float* WcX2 = (const float*)d_in[6];
    const float* bcX2 = (const float*)d_in[7];
    const float* WcY1 = (const float*)d_in[8];
    const float* bcY1 = (const float*)d_in[9];
    const float* WcY2 = (const float*)d_in[10];
    const float* bcY2 = (const float*)d_in[11];
    const float* W0   = (const float*)d_in[12];
    const float* b0   = (const float*)d_in[13];
    const float* W1   = (const float*)d_in[14];
    const float* b1   = (const float*)d_in[15];
    const float* W2   = (const float*)d_in[16];
    const float* b2   = (const float*)d_in[17];
    const int* idx0   = (const int*)d_in[18];
    const int* idx1   = (const int*)d_in[19];
    float* out        = (float*)d_out;

    const int Btot = in_sizes[18];
    const int blocks = (Btot + PPB - 1) / PPB;
    mf_fused<<<blocks, NT, 0, stream>>>(X, Y, xatt, yatt,
                                        WcX1, bcX1, WcX2, bcX2,
                                        WcY1, bcY1, WcY2, bcY2,
                                        W0, b0, W1, b1, W2, b2,
                                        idx0, idx1, out, Btot);
}

// Round 3
// 258.774 us; speedup vs baseline: 1.8795x; 1.8795x over previous
//
#include <hip/hip_runtime.h>
#include <hip/hip_bf16.h>

#define S_   4
#define N_   16384
#define K_   128

typedef __attribute__((ext_vector_type(8))) short short8v;   // 8 bf16 = 4 VGPR
typedef __attribute__((ext_vector_type(4))) float f32x4;

__device__ __forceinline__ float lrelu(float x) { return x > 0.f ? x : 0.01f * x; }

__device__ __forceinline__ unsigned short f2bf(float f) {
    union { float f; unsigned u; } v; v.f = f;
    unsigned r = v.u + 0x7fff + ((v.u >> 16) & 1);   // round-to-nearest-even
    return (unsigned short)(r >> 16);
}

// ---------------------------------------------------------------------------
// Kernel 1: convert W0 [256,128] f32 -> W0T [128][256] bf16 (transposed),
//           W1 [128,64]  f32 -> W1T [64][128]  bf16.
// Transposed so MFMA B-fragments (col-major, 8 contiguous K) are 16B loads.
// ---------------------------------------------------------------------------
__global__ __launch_bounds__(256)
void convert_w(const float* __restrict__ W0, const float* __restrict__ W1,
               unsigned short* __restrict__ W0T, unsigned short* __restrict__ W1T)
{
    int t = blockIdx.x * 256 + threadIdx.x;
    if (t < 128 * 256) {                 // W0T[n][k] = W0[k][n]
        int n = t >> 8, k = t & 255;
        W0T[t] = f2bf(W0[k * 128 + n]);
    }
    t -= 128 * 256;
    if (t >= 0 && t < 64 * 128) {        // W1T[n][k] = W1[k][n]
        int n = t >> 7, k = t & 127;
        W1T[t] = f2bf(W1[k * 64 + n]);
    }
}

// ---------------------------------------------------------------------------
// Kernel 2: embedding. One wave per pair: lanes 0-31 do side X, 32-63 side Y.
// Each lane owns 4 consecutive k (k0=4*(lane&31)). No LDS, no barriers.
// Writes feat[pair][256] bf16 (X embed cols 0..127, Y embed cols 128..255).
// ---------------------------------------------------------------------------
__global__ __launch_bounds__(256)
void embed_kernel(const float* __restrict__ X, const float* __restrict__ Y,
                  const float* __restrict__ x_att, const float* __restrict__ y_att,
                  const float* __restrict__ WcX1, const float* __restrict__ bcX1,
                  const float* __restrict__ WcX2, const float* __restrict__ bcX2,
                  const float* __restrict__ WcY1, const float* __restrict__ bcY1,
                  const float* __restrict__ WcY2, const float* __restrict__ bcY2,
                  const int* __restrict__ idx0, const int* __restrict__ idx1,
                  unsigned short* __restrict__ feat, int Btot)
{
    const int pair = blockIdx.x * 4 + (threadIdx.x >> 6);
    if (pair >= Btot) return;
    const int lane = threadIdx.x & 63;
    const int half = lane >> 5;          // 0 = X side, 1 = Y side
    const int sl   = lane & 31;
    const int k0   = sl * 4;

    const float* Z    = half ? Y    : X;
    const float* Wc1  = half ? WcY1 : WcX1;
    const float* Wc2  = half ? WcY2 : WcX2;
    const float* bc2h = half ? bcY2 : bcX2;
    const float  bc1v = half ? bcY1[0] : bcX1[0];
    const float* attv = half ? y_att : x_att;
    const int    idx  = half ? idx1[pair] : idx0[pair];

    // view softmax (4 scalars)
    float a0 = attv[0], a1 = attv[1], a2 = attv[2], a3 = attv[3];
    float am = fmaxf(fmaxf(a0, a1), fmaxf(a2, a3));
    float sw0 = __expf(a0 - am), sw1 = __expf(a1 - am),
          sw2 = __expf(a2 - am), sw3 = __expf(a3 - am);
    float swinv = 1.f / (sw0 + sw1 + sw2 + sw3);
    sw0 *= swinv; sw1 *= swinv; sw2 *= swinv; sw3 *= swinv;

    // gather 4 view rows (coalesced 512B rows per 32-lane half)
    float4 z0 = *(const float4*)(Z + ((size_t)0 * N_ + idx) * K_ + k0);
    float4 z1 = *(const float4*)(Z + ((size_t)1 * N_ + idx) * K_ + k0);
    float4 z2 = *(const float4*)(Z + ((size_t)2 * N_ + idx) * K_ + k0);
    float4 z3 = *(const float4*)(Z + ((size_t)3 * N_ + idx) * K_ + k0);

    float4 zs;
    zs.x = z0.x + z1.x + z2.x + z3.x;
    zs.y = z0.y + z1.y + z2.y + z3.y;
    zs.z = z0.z + z1.z + z2.z + z3.z;
    zs.w = z0.w + z1.w + z2.w + z3.w;

    // dp = dot(Zcat, Wc1) over S*K, partial per lane then 32-lane butterfly
    float4 w0 = *(const float4*)(Wc1 + 0 * K_ + k0);
    float4 w1 = *(const float4*)(Wc1 + 1 * K_ + k0);
    float4 w2 = *(const float4*)(Wc1 + 2 * K_ + k0);
    float4 w3 = *(const float4*)(Wc1 + 3 * K_ + k0);
    float dp = z0.x*w0.x + z0.y*w0.y + z0.z*w0.z + z0.w*w0.w
             + z1.x*w1.x + z1.y*w1.y + z1.z*w1.z + z1.w*w1.w
             + z2.x*w2.x + z2.y*w2.y + z2.z*w2.z + z2.w*w2.w
             + z3.x*w3.x + z3.y*w3.y + z3.z*w3.z + z3.w*w3.w;
#pragma unroll
    for (int off = 16; off >= 1; off >>= 1) dp += __shfl_xor(dp, off, 64);

    float a = lrelu(dp + bc1v);

    // attention logits over K, softmax within 32-lane half
    float4 c2 = *(const float4*)(Wc2 + k0);
    float4 cb = *(const float4*)(bc2h + k0);
    float l0 = fmaf(a, c2.x, cb.x), l1 = fmaf(a, c2.y, cb.y);
    float l2 = fmaf(a, c2.z, cb.z), l3 = fmaf(a, c2.w, cb.w);
    float m = fmaxf(fmaxf(l0, l1), fmaxf(l2, l3));
#pragma unroll
    for (int off = 16; off >= 1; off >>= 1) m = fmaxf(m, __shfl_xor(m, off, 64));
    float e0 = __expf(l0 - m), e1 = __expf(l1 - m),
          e2 = __expf(l2 - m), e3 = __expf(l3 - m);
    float s = e0 + e1 + e2 + e3;
#pragma unroll
    for (int off = 16; off >= 1; off >>= 1) s += __shfl_xor(s, off, 64);
    float inv = 1.f / s;

    // e8 + combine
    float o0v = 0.5f * (zs.x * (e0 * inv) + (sw0*z0.x + sw1*z1.x + sw2*z2.x + sw3*z3.x));
    float o1v = 0.5f * (zs.y * (e1 * inv) + (sw0*z0.y + sw1*z1.y + sw2*z2.y + sw3*z3.y));
    float o2v = 0.5f * (zs.z * (e2 * inv) + (sw0*z0.z + sw1*z1.z + sw2*z2.z + sw3*z3.z));
    float o3v = 0.5f * (zs.w * (e3 * inv) + (sw0*z0.w + sw1*z1.w + sw2*z2.w + sw3*z3.w));

    ushort4 p;
    p.x = f2bf(o0v); p.y = f2bf(o1v); p.z = f2bf(o2v); p.w = f2bf(o3v);
    *(ushort4*)(feat + (size_t)pair * 256 + half * 128 + k0) = p;
}

// ---------------------------------------------------------------------------
// Kernel 3: MFMA decoder. 128 rows/block, 4 waves, 32 rows/wave.
// Layer0: feat[B,256]b @ W0T -> acc (16x16x32 MFMA, A from global, B from L2)
// o0 -> LDS (+8-elem pad, conflict-free) -> layer1 MFMA -> layer2 dot+sigmoid.
// Waves are fully independent: no __syncthreads anywhere.
// ---------------------------------------------------------------------------
__global__ __launch_bounds__(256)
void decoder_kernel(const unsigned short* __restrict__ feat,
                    const unsigned short* __restrict__ W0T,
                    const unsigned short* __restrict__ W1T,
                    const float* __restrict__ b0, const float* __restrict__ b1,
                    const float* __restrict__ W2, const float* __restrict__ b2,
                    float* __restrict__ out, int Btot)
{
    __shared__ unsigned short o0[128 * 136];   // 136 = 128 + 8 pad (272B stride)

    const int wave = threadIdx.x >> 6;
    const int lane = threadIdx.x & 63;
    const int lx   = lane & 15;     // row (A) / col (B) index inside tile
    const int lk   = lane >> 4;     // k-group: k = lk*8 .. +7
    const int rowBase = blockIdx.x * 128 + wave * 32;

    // ---------------- layer 0: [32,256] @ [256,128] ----------------
    f32x4 acc[2][8];
#pragma unroll
    for (int m = 0; m < 2; ++m)
#pragma unroll
        for (int n = 0; n < 8; ++n) acc[m][n] = (f32x4)0.f;

    const unsigned short* fa0 = feat + (size_t)(rowBase + lx) * 256;
    const unsigned short* fa1 = feat + (size_t)(rowBase + 16 + lx) * 256;
#pragma unroll
    for (int kk = 0; kk < 8; ++kk) {
        const int koff = kk * 32 + lk * 8;
        short8v a0 = *(const short8v*)(fa0 + koff);
        short8v a1 = *(const short8v*)(fa1 + koff);
#pragma unroll
        for (int n = 0; n < 8; ++n) {
            short8v b = *(const short8v*)(W0T + (size_t)(n * 16 + lx) * 256 + koff);
            acc[0][n] = __builtin_amdgcn_mfma_f32_16x16x32_bf16(a0, b, acc[0][n], 0, 0, 0);
            acc[1][n] = __builtin_amdgcn_mfma_f32_16x16x32_bf16(a1, b, acc[1][n], 0, 0, 0);
        }
    }

    // epilogue: +b0, lrelu, bf16 -> LDS o0 (C/D map: col=lane&15, row=(lane>>4)*4+r)
    {
        float b0v[8];
#pragma unroll
        for (int n = 0; n < 8; ++n) b0v[n] = b0[n * 16 + lx];
#pragma unroll
        for (int m = 0; m < 2; ++m)
#pragma unroll
            for (int n = 0; n < 8; ++n)
#pragma unroll
                for (int r = 0; r < 4; ++r) {
                    float v = lrelu(acc[m][n][r] + b0v[n]);
                    int row = wave * 32 + m * 16 + lk * 4 + r;
                    o0[row * 136 + n * 16 + lx] = f2bf(v);
                }
    }
    // wave reads only its own writes; compiler inserts lgkmcnt waits.

    // ---------------- layer 1: [32,128] @ [128,64] ----------------
    f32x4 acc1[2][4];
#pragma unroll
    for (int m = 0; m < 2; ++m)
#pragma unroll
        for (int n = 0; n < 4; ++n) acc1[m][n] = (f32x4)0.f;

#pragma unroll
    for (int kk = 0; kk < 4; ++kk) {
        const int koff = kk * 32 + lk * 8;
        short8v a0 = *(const short8v*)(&o0[(wave * 32 + lx) * 136 + koff]);
        short8v a1 = *(const short8v*)(&o0[(wave * 32 + 16 + lx) * 136 + koff]);
#pragma unroll
        for (int n = 0; n < 4; ++n) {
            short8v b = *(const short8v*)(W1T + (size_t)(n * 16 + lx) * 128 + koff);
            acc1[0][n] = __builtin_amdgcn_mfma_f32_16x16x32_bf16(a0, b, acc1[0][n], 0, 0, 0);
            acc1[1][n] = __builtin_amdgcn_mfma_f32_16x16x32_bf16(a1, b, acc1[1][n], 0, 0, 0);
        }
    }

    // ---------------- layer 2: o1[32,64] . W2[64] + b2, sigmoid ----------------
    {
        float w2v[4], b1v[4];
#pragma unroll
        for (int n = 0; n < 4; ++n) {
            w2v[n] = W2[n * 16 + lx];
            b1v[n] = b1[n * 16 + lx];
        }
        const float b2v = b2[0];
        float t[2][4];
#pragma unroll
        for (int m = 0; m < 2; ++m)
#pragma unroll
            for (int r = 0; r < 4; ++r) t[m][r] = 0.f;
#pragma unroll
        for (int m = 0; m < 2; ++m)
#pragma unroll
            for (int n = 0; n < 4; ++n)
#pragma unroll
                for (int r = 0; r < 4; ++r) {
                    float v = lrelu(acc1[m][n][r] + b1v[n]);
                    t[m][r] = fmaf(v, w2v[n], t[m][r]);
                }
        // reduce over the 16 lanes (lx) that hold different cols of the same row
#pragma unroll
        for (int off = 8; off >= 1; off >>= 1)
#pragma unroll
            for (int m = 0; m < 2; ++m)
#pragma unroll
                for (int r = 0; r < 4; ++r)
                    t[m][r] += __shfl_xor(t[m][r], off, 64);
        if (lx == 0) {
#pragma unroll
            for (int m = 0; m < 2; ++m)
#pragma unroll
                for (int r = 0; r < 4; ++r) {
                    int row = rowBase + m * 16 + lk * 4 + r;
                    if (row < Btot)
                        out[row] = 1.f / (1.f + __expf(-(t[m][r] + b2v)));
                }
        }
    }
}

// ---------------------------------------------------------------------------
// Fallback (round-1 fused kernel) if ws is too small for the split pipeline.
// ---------------------------------------------------------------------------
#define PPB  32
#define NT   256
#define FSTR 260
#define O0STR 132
#define O1STR 68

__device__ __forceinline__ void embed_side_f(
    const float* __restrict__ Z, int idx,
    const float* __restrict__ Wc1, float bc1v,
    const float* __restrict__ Wc2, const float* __restrict__ bc2,
    float sw0, float sw1, float sw2, float sw3,
    int lane, float* dst)
{
    const int k0 = 2 * lane;
    const float* base = Z + (size_t)idx * K_ + k0;
    float2 z0 = *(const float2*)(base + (size_t)0 * N_ * K_);
    float2 z1 = *(const float2*)(base + (size_t)1 * N_ * K_);
    float2 z2 = *(const float2*)(base + (size_t)2 * N_ * K_);
    float2 z3 = *(const float2*)(base + (size_t)3 * N_ * K_);
    float zs0 = z0.x + z1.x + z2.x + z3.x;
    float zs1 = z0.y + z1.y + z2.y + z3.y;
    float2 w0 = *(const float2*)(Wc1 + 0 * K_ + k0);
    float2 w1 = *(const float2*)(Wc1 + 1 * K_ + k0);
    float2 w2 = *(const float2*)(Wc1 + 2 * K_ + k0);
    float2 w3 = *(const float2*)(Wc1 + 3 * K_ + k0);
    float dp = z0.x*w0.x + z0.y*w0.y + z1.x*w1.x + z1.y*w1.y
             + z2.x*w2.x + z2.y*w2.y + z3.x*w3.x + z3.y*w3.y;
#pragma unroll
    for (int off = 32; off >= 1; off >>= 1) dp += __shfl_xor(dp, off, 64);
    float a = lrelu(dp + bc1v);
    float2 c2 = *(const float2*)(Wc2 + k0);
    float2 cb = *(const float2*)(bc2 + k0);
    float l0 = fmaf(a, c2.x, cb.x), l1 = fmaf(a, c2.y, cb.y);
    float m = fmaxf(l0, l1);
#pragma unroll
    for (int off = 32; off >= 1; off >>= 1) m = fmaxf(m, __shfl_xor(m, off, 64));
    float e0 = __expf(l0 - m), e1 = __expf(l1 - m);
    float s = e0 + e1;
#pragma unroll
    for (int off = 32; off >= 1; off >>= 1) s += __shfl_xor(s, off, 64);
    float inv = 1.f / s;
    float e8a = sw0*z0.x + sw1*z1.x + sw2*z2.x + sw3*z3.x;
    float e8b = sw0*z0.y + sw1*z1.y + sw2*z2.y + sw3*z3.y;
    *(float2*)(dst + k0) = make_float2(0.5f*(zs0*(e0*inv)+e8a), 0.5f*(zs1*(e1*inv)+e8b));
}

__global__ __launch_bounds__(NT)
void mf_fused(const float* __restrict__ X, const float* __restrict__ Y,
              const float* __restrict__ x_att, const float* __restrict__ y_att,
              const float* __restrict__ WcX1, const float* __restrict__ bcX1,
              const float* __restrict__ WcX2, const float* __restrict__ bcX2,
              const float* __restrict__ WcY1, const float* __restrict__ bcY1,
              const float* __restrict__ WcY2, const float* __restrict__ bcY2,
              const float* __restrict__ W0, const float* __restrict__ b0,
              const float* __restrict__ W1, const float* __restrict__ b1,
              const float* __restrict__ W2, const float* __restrict__ b2,
              const int* __restrict__ idx0, const int* __restrict__ idx1,
              float* __restrict__ out, int Btot)
{
    __shared__ float pool[PPB * FSTR];
    float* feat = pool;
    const int tid  = threadIdx.x;
    const int lane = tid & 63;
    const int wave = tid >> 6;
    float swx0, swx1, swx2, swx3, swy0, swy1, swy2, swy3;
    {
        float a0 = x_att[0], a1 = x_att[1], a2 = x_att[2], a3 = x_att[3];
        float m = fmaxf(fmaxf(a0, a1), fmaxf(a2, a3));
        float e0 = __expf(a0-m), e1 = __expf(a1-m), e2 = __expf(a2-m), e3 = __expf(a3-m);
        float inv = 1.f / (e0+e1+e2+e3);
        swx0=e0*inv; swx1=e1*inv; swx2=e2*inv; swx3=e3*inv;
        float b0v=y_att[0], b1v=y_att[1], b2v=y_att[2], b3v=y_att[3];
        float my = fmaxf(fmaxf(b0v,b1v), fmaxf(b2v,b3v));
        float f0=__expf(b0v-my), f1=__expf(b1v-my), f2=__expf(b2v-my), f3=__expf(b3v-my);
        float invy = 1.f/(f0+f1+f2+f3);
        swy0=f0*invy; swy1=f1*invy; swy2=f2*invy; swy3=f3*invy;
    }
    const float bcX1v = bcX1[0], bcY1v = bcY1[0];
    const long pair_base = (long)blockIdx.x * PPB;
    for (int pp = 0; pp < PPB/4; ++pp) {
        const int p_local = wave * (PPB/4) + pp;
        const long pair = pair_base + p_local;
        if (pair < Btot) {
            embed_side_f(X, idx0[pair], WcX1, bcX1v, WcX2, bcX2, swx0,swx1,swx2,swx3, lane, feat + p_local*FSTR);
            embed_side_f(Y, idx1[pair], WcY1, bcY1v, WcY2, bcY2, swy0,swy1,swy2,swy3, lane, feat + p_local*FSTR + K_);
        }
    }
    __syncthreads();
    const int jg = tid & 15, pg = tid >> 4;
    float acc[2][8];
#pragma unroll
    for (int p=0;p<2;++p)
#pragma unroll
        for (int j=0;j<8;++j) acc[p][j]=0.f;
    const float* frow0 = feat + (pg*2+0)*FSTR;
    const float* frow1 = feat + (pg*2+1)*FSTR;
    for (int i = 0; i < 2*K_; i += 4) {
        float fav[4], fbv[4];
        *(float4*)fav = *(const float4*)(frow0+i);
        *(float4*)fbv = *(const float4*)(frow1+i);
#pragma unroll
        for (int u=0;u<4;++u) {
            float wv[8];
            *(float4*)(wv)   = *(const float4*)(W0 + (i+u)*K_ + jg*8);
            *(float4*)(wv+4) = *(const float4*)(W0 + (i+u)*K_ + jg*8 + 4);
#pragma unroll
            for (int j=0;j<8;++j) {
                acc[0][j] = fmaf(fav[u], wv[j], acc[0][j]);
                acc[1][j] = fmaf(fbv[u], wv[j], acc[1][j]);
            }
        }
    }
    __syncthreads();
    float* o0 = pool;
    {
        float bv[8];
        *(float4*)bv     = *(const float4*)(b0 + jg*8);
        *(float4*)(bv+4) = *(const float4*)(b0 + jg*8 + 4);
#pragma unroll
        for (int p=0;p<2;++p) {
            float v[8];
#pragma unroll
            for (int j=0;j<8;++j) v[j] = lrelu(acc[p][j] + bv[j]);
            *(float4*)(o0 + (pg*2+p)*O0STR + jg*8)     = *(float4*)v;
            *(float4*)(o0 + (pg*2+p)*O0STR + jg*8 + 4) = *(float4*)(v+4);
        }
    }
    __syncthreads();
    float acc1[2][4];
#pragma unroll
    for (int p=0;p<2;++p)
#pragma unroll
        for (int j=0;j<4;++j) acc1[p][j]=0.f;
    const float* r0 = o0 + (pg*2+0)*O0STR;
    const float* r1 = o0 + (pg*2+1)*O0STR;
    for (int i = 0; i < K_; i += 4) {
        float fav[4], fbv[4];
        *(float4*)fav = *(const float4*)(r0+i);
        *(float4*)fbv = *(const float4*)(r1+i);
#pragma unroll
        for (int u=0;u<4;++u) {
            float wv[4];
            *(float4*)wv = *(const float4*)(W1 + (i+u)*(K_/2) + jg*4);
#pragma unroll
            for (int j=0;j<4;++j) {
                acc1[0][j] = fmaf(fav[u], wv[j], acc1[0][j]);
                acc1[1][j] = fmaf(fbv[u], wv[j], acc1[1][j]);
            }
        }
    }
    float* o1 = pool + PPB*O0STR;
    {
        float bv[4];
        *(float4*)bv = *(const float4*)(b1 + jg*4);
#pragma unroll
        for (int p=0;p<2;++p) {
            float v[4];
#pragma unroll
            for (int j=0;j<4;++j) v[j] = lrelu(acc1[p][j] + bv[j]);
            *(float4*)(o1 + (pg*2+p)*O1STR + jg*4) = *(float4*)v;
        }
    }
    __syncthreads();
    {
        const int p = tid >> 3, part = tid & 7;
        const float* r = o1 + p*O1STR + part*8;
        float rv[8], wv[8];
        *(float4*)rv     = *(const float4*)(r);
        *(float4*)(rv+4) = *(const float4*)(r+4);
        *(float4*)wv     = *(const float4*)(W2 + part*8);
        *(float4*)(wv+4) = *(const float4*)(W2 + part*8 + 4);
        float d = 0.f;
#pragma unroll
        for (int j=0;j<8;++j) d = fmaf(rv[j], wv[j], d);
        d += __shfl_xor(d, 1, 64);
        d += __shfl_xor(d, 2, 64);
        d += __shfl_xor(d, 4, 64);
        if (part == 0) {
            const long pair = pair_base + p;
            if (pair < Btot) out[pair] = 1.f / (1.f + __expf(-(d + b2[0])));
        }
    }
}

// ---------------------------------------------------------------------------
extern "C" void kernel_launch(void* const* d_in, const int* in_sizes, int n_in,
                              void* d_out, int out_size, void* d_ws, size_t ws_size,
                              hipStream_t stream) {
    const float* X    = (const float*)d_in[0];
    const float* Y    = (const float*)d_in[1];
    const float* xatt = (const float*)d_in[2];
    const float* yatt = (const float*)d_in[3];
    const float* WcX1 = (const float*)d_in[4];
    const float* bcX1 = (const float*)d_in[5];
    const float* WcX2 = (const float*)d_in[6];
    const float* bcX2 = (const float*)d_in[7];
    const float* WcY1 = (const float*)d_in[8];
    const float* bcY1 = (const float*)d_in[9];
    const float* WcY2 = (const float*)d_in[10];
    const float* bcY2 = (const float*)d_in[11];
    const float* W0   = (const float*)d_in[12];
    const float* b0   = (const float*)d_in[13];
    const float* W1   = (const float*)d_in[14];
    const float* b1   = (const float*)d_in[15];
    const float* W2   = (const float*)d_in[16];
    const float* b2   = (const float*)d_in[17];
    const int* idx0   = (const int*)d_in[18];
    const int* idx1   = (const int*)d_in[19];
    float* out        = (float*)d_out;

    const int Btot = in_sizes[18];
    const int dblocks = (Btot + 127) / 128;
    const size_t Bpad = (size_t)dblocks * 128;
    const size_t need = (1 << 20) + Bpad * 512;   // 1MB weights area + feat

    if (ws_size >= need) {
        unsigned short* W0T  = (unsigned short*)d_ws;
        unsigned short* W1T  = (unsigned short*)((char*)d_ws + 65536);
        unsigned short* feat = (unsigned short*)((char*)d_ws + (1 << 20));

        convert_w<<<(128*256 + 64*128 + 255) / 256, 256, 0, stream>>>(W0, W1, W0T, W1T);
        embed_kernel<<<(Btot + 3) / 4, 256, 0, stream>>>(
            X, Y, xatt, yatt, WcX1, bcX1, WcX2, bcX2,
            WcY1, bcY1, WcY2, bcY2, idx0, idx1, feat, Btot);
        decoder_kernel<<<dblocks, 256, 0, stream>>>(
            feat, W0T, W1T, b0, b1, W2, b2, out, Btot);
    } else {
        mf_fused<<<(Btot + PPB - 1) / PPB, NT, 0, stream>>>(
            X, Y, xatt, yatt, WcX1, bcX1, WcX2, bcX2,
            WcY1, bcY1, WcY2, bcY2, W0, b0, W1, b1, W2, b2,
            idx0, idx1, out, Btot);
    }
}

// Round 4
// 196.621 us; speedup vs baseline: 2.4737x; 1.3161x over previous
//
#include <hip/hip_runtime.h>
#include <hip/hip_bf16.h>

#define S_   4
#define N_   16384
#define K_   128

typedef __attribute__((ext_vector_type(8))) short short8v;   // 8 bf16 = 4 VGPR
typedef __attribute__((ext_vector_type(4))) float f32x4;

__device__ __forceinline__ float lrelu(float x) { return x > 0.f ? x : 0.01f * x; }

__device__ __forceinline__ unsigned short f2bf(float f) {
    union { float f; unsigned u; } v; v.f = f;
    unsigned r = v.u + 0x7fff + ((v.u >> 16) & 1);   // round-to-nearest-even
    return (unsigned short)(r >> 16);
}

// ---------------------------------------------------------------------------
// Kernel 1: convert W0 [256,128] f32 -> W0T [128][256] bf16 (transposed),
//           W1 [128,64]  f32 -> W1T [64][128]  bf16.
// ---------------------------------------------------------------------------
__global__ __launch_bounds__(256)
void convert_w(const float* __restrict__ W0, const float* __restrict__ W1,
               unsigned short* __restrict__ W0T, unsigned short* __restrict__ W1T)
{
    int t = blockIdx.x * 256 + threadIdx.x;
    if (t < 128 * 256) {                 // W0T[n][k] = W0[k][n]
        int n = t >> 8, k = t & 255;
        W0T[t] = f2bf(W0[k * 128 + n]);
    }
    t -= 128 * 256;
    if (t >= 0 && t < 64 * 128) {        // W1T[n][k] = W1[k][n]
        int n = t >> 7, k = t & 127;
        W1T[t] = f2bf(W1[k * 64 + n]);
    }
}

// ---------------------------------------------------------------------------
// Kernel 2: NODE embedding (key change vs R3: embedding is a pure function of
// the node, so compute it once per node, not once per pair — 8x less work).
// One wave per node: lanes 0-31 side X, lanes 32-63 side Y. Fully coalesced
// sequential reads of X and Y (no gather). Writes Xemb[N][128], Yemb[N][128]
// as bf16 (8.4 MB total, stays L2/L3-resident for the decoder's gathers).
// ---------------------------------------------------------------------------
__global__ __launch_bounds__(256)
void node_embed(const float* __restrict__ X, const float* __restrict__ Y,
                const float* __restrict__ x_att, const float* __restrict__ y_att,
                const float* __restrict__ WcX1, const float* __restrict__ bcX1,
                const float* __restrict__ WcX2, const float* __restrict__ bcX2,
                const float* __restrict__ WcY1, const float* __restrict__ bcY1,
                const float* __restrict__ WcY2, const float* __restrict__ bcY2,
                unsigned short* __restrict__ Xemb, unsigned short* __restrict__ Yemb)
{
    const int node = blockIdx.x * 4 + (threadIdx.x >> 6);
    if (node >= N_) return;
    const int lane = threadIdx.x & 63;
    const int half = lane >> 5;          // 0 = X side, 1 = Y side
    const int sl   = lane & 31;
    const int k0   = sl * 4;

    const float* Z    = half ? Y    : X;
    const float* Wc1  = half ? WcY1 : WcX1;
    const float* Wc2  = half ? WcY2 : WcX2;
    const float* bc2h = half ? bcY2 : bcX2;
    const float  bc1v = half ? bcY1[0] : bcX1[0];
    const float* attv = half ? y_att : x_att;
    unsigned short* dst = half ? Yemb : Xemb;

    // view softmax (4 scalars)
    float a0 = attv[0], a1 = attv[1], a2 = attv[2], a3 = attv[3];
    float am = fmaxf(fmaxf(a0, a1), fmaxf(a2, a3));
    float sw0 = __expf(a0 - am), sw1 = __expf(a1 - am),
          sw2 = __expf(a2 - am), sw3 = __expf(a3 - am);
    float swinv = 1.f / (sw0 + sw1 + sw2 + sw3);
    sw0 *= swinv; sw1 *= swinv; sw2 *= swinv; sw3 *= swinv;

    // sequential coalesced reads: 4 view rows of this node
    float4 z0 = *(const float4*)(Z + ((size_t)0 * N_ + node) * K_ + k0);
    float4 z1 = *(const float4*)(Z + ((size_t)1 * N_ + node) * K_ + k0);
    float4 z2 = *(const float4*)(Z + ((size_t)2 * N_ + node) * K_ + k0);
    float4 z3 = *(const float4*)(Z + ((size_t)3 * N_ + node) * K_ + k0);

    float4 zs;
    zs.x = z0.x + z1.x + z2.x + z3.x;
    zs.y = z0.y + z1.y + z2.y + z3.y;
    zs.z = z0.z + z1.z + z2.z + z3.z;
    zs.w = z0.w + z1.w + z2.w + z3.w;

    // dp = dot(Zcat, Wc1), 32-lane butterfly within each half
    float4 w0 = *(const float4*)(Wc1 + 0 * K_ + k0);
    float4 w1 = *(const float4*)(Wc1 + 1 * K_ + k0);
    float4 w2 = *(const float4*)(Wc1 + 2 * K_ + k0);
    float4 w3 = *(const float4*)(Wc1 + 3 * K_ + k0);
    float dp = z0.x*w0.x + z0.y*w0.y + z0.z*w0.z + z0.w*w0.w
             + z1.x*w1.x + z1.y*w1.y + z1.z*w1.z + z1.w*w1.w
             + z2.x*w2.x + z2.y*w2.y + z2.z*w2.z + z2.w*w2.w
             + z3.x*w3.x + z3.y*w3.y + z3.z*w3.z + z3.w*w3.w;
#pragma unroll
    for (int off = 16; off >= 1; off >>= 1) dp += __shfl_xor(dp, off, 64);

    float a = lrelu(dp + bc1v);

    // attention logits over K, softmax within 32-lane half
    float4 c2 = *(const float4*)(Wc2 + k0);
    float4 cb = *(const float4*)(bc2h + k0);
    float l0 = fmaf(a, c2.x, cb.x), l1 = fmaf(a, c2.y, cb.y);
    float l2 = fmaf(a, c2.z, cb.z), l3 = fmaf(a, c2.w, cb.w);
    float m = fmaxf(fmaxf(l0, l1), fmaxf(l2, l3));
#pragma unroll
    for (int off = 16; off >= 1; off >>= 1) m = fmaxf(m, __shfl_xor(m, off, 64));
    float e0 = __expf(l0 - m), e1 = __expf(l1 - m),
          e2 = __expf(l2 - m), e3 = __expf(l3 - m);
    float s = e0 + e1 + e2 + e3;
#pragma unroll
    for (int off = 16; off >= 1; off >>= 1) s += __shfl_xor(s, off, 64);
    float inv = 1.f / s;

    float o0v = 0.5f * (zs.x * (e0 * inv) + (sw0*z0.x + sw1*z1.x + sw2*z2.x + sw3*z3.x));
    float o1v = 0.5f * (zs.y * (e1 * inv) + (sw0*z0.y + sw1*z1.y + sw2*z2.y + sw3*z3.y));
    float o2v = 0.5f * (zs.z * (e2 * inv) + (sw0*z0.z + sw1*z1.z + sw2*z2.z + sw3*z3.z));
    float o3v = 0.5f * (zs.w * (e3 * inv) + (sw0*z0.w + sw1*z1.w + sw2*z2.w + sw3*z3.w));

    ushort4 p;
    p.x = f2bf(o0v); p.y = f2bf(o1v); p.z = f2bf(o2v); p.w = f2bf(o3v);
    *(ushort4*)(dst + (size_t)node * K_ + k0) = p;
}

// ---------------------------------------------------------------------------
// Kernel 3: MFMA decoder. 128 rows/block, 4 waves, 32 rows/wave.
// A-fragments gathered directly from Xemb/Yemb via idx0/idx1 (16B per lane,
// 8.4MB table -> L2/L3-resident). feat is never materialized.
// o0 -> padded LDS (transpose for layer1) -> layer1 MFMA -> layer2 + sigmoid.
// Waves fully independent: no __syncthreads.
// ---------------------------------------------------------------------------
__global__ __launch_bounds__(256)
void decoder_kernel(const unsigned short* __restrict__ Xemb,
                    const unsigned short* __restrict__ Yemb,
                    const unsigned short* __restrict__ W0T,
                    const unsigned short* __restrict__ W1T,
                    const float* __restrict__ b0, const float* __restrict__ b1,
                    const float* __restrict__ W2, const float* __restrict__ b2,
                    const int* __restrict__ idx0, const int* __restrict__ idx1,
                    float* __restrict__ out, int Btot)
{
    __shared__ unsigned short o0[128 * 136];   // 136 = 128 + 8 pad (272B stride)

    const int wave = threadIdx.x >> 6;
    const int lane = threadIdx.x & 63;
    const int lx   = lane & 15;     // row (A) / col (B) index inside tile
    const int lk   = lane >> 4;     // k-group: k = lk*8 .. +7
    const int rowBase = blockIdx.x * 128 + wave * 32;

    // per-lane gather rows (clamped; B is a multiple of 128 in practice)
    int r0 = rowBase + lx;       if (r0 >= Btot) r0 = Btot - 1;
    int r1 = rowBase + 16 + lx;  if (r1 >= Btot) r1 = Btot - 1;
    const unsigned short* xb0 = Xemb + (size_t)idx0[r0] * K_;
    const unsigned short* xb1 = Xemb + (size_t)idx0[r1] * K_;
    const unsigned short* yb0 = Yemb + (size_t)idx1[r0] * K_;
    const unsigned short* yb1 = Yemb + (size_t)idx1[r1] * K_;

    // ---------------- layer 0: [32,256] @ [256,128] ----------------
    f32x4 acc[2][8];
#pragma unroll
    for (int m = 0; m < 2; ++m)
#pragma unroll
        for (int n = 0; n < 8; ++n) acc[m][n] = (f32x4)0.f;

#pragma unroll
    for (int kk = 0; kk < 8; ++kk) {
        const int koff = kk * 32 + lk * 8;
        short8v a0, a1;
        if (kk < 4) {           // feature cols 0..127 = X embedding
            a0 = *(const short8v*)(xb0 + koff);
            a1 = *(const short8v*)(xb1 + koff);
        } else {                // feature cols 128..255 = Y embedding
            a0 = *(const short8v*)(yb0 + koff - 128);
            a1 = *(const short8v*)(yb1 + koff - 128);
        }
#pragma unroll
        for (int n = 0; n < 8; ++n) {
            short8v b = *(const short8v*)(W0T + (size_t)(n * 16 + lx) * 256 + koff);
            acc[0][n] = __builtin_amdgcn_mfma_f32_16x16x32_bf16(a0, b, acc[0][n], 0, 0, 0);
            acc[1][n] = __builtin_amdgcn_mfma_f32_16x16x32_bf16(a1, b, acc[1][n], 0, 0, 0);
        }
    }

    // epilogue: +b0, lrelu, bf16 -> LDS o0 (C/D map: col=lane&15, row=(lane>>4)*4+r)
    {
        float b0v[8];
#pragma unroll
        for (int n = 0; n < 8; ++n) b0v[n] = b0[n * 16 + lx];
#pragma unroll
        for (int m = 0; m < 2; ++m)
#pragma unroll
            for (int n = 0; n < 8; ++n)
#pragma unroll
                for (int r = 0; r < 4; ++r) {
                    float v = lrelu(acc[m][n][r] + b0v[n]);
                    int row = wave * 32 + m * 16 + lk * 4 + r;
                    o0[row * 136 + n * 16 + lx] = f2bf(v);
                }
    }
    // wave reads only its own writes; compiler inserts lgkmcnt waits.

    // ---------------- layer 1: [32,128] @ [128,64] ----------------
    f32x4 acc1[2][4];
#pragma unroll
    for (int m = 0; m < 2; ++m)
#pragma unroll
        for (int n = 0; n < 4; ++n) acc1[m][n] = (f32x4)0.f;

#pragma unroll
    for (int kk = 0; kk < 4; ++kk) {
        const int koff = kk * 32 + lk * 8;
        short8v a0 = *(const short8v*)(&o0[(wave * 32 + lx) * 136 + koff]);
        short8v a1 = *(const short8v*)(&o0[(wave * 32 + 16 + lx) * 136 + koff]);
#pragma unroll
        for (int n = 0; n < 4; ++n) {
            short8v b = *(const short8v*)(W1T + (size_t)(n * 16 + lx) * 128 + koff);
            acc1[0][n] = __builtin_amdgcn_mfma_f32_16x16x32_bf16(a0, b, acc1[0][n], 0, 0, 0);
            acc1[1][n] = __builtin_amdgcn_mfma_f32_16x16x32_bf16(a1, b, acc1[1][n], 0, 0, 0);
        }
    }

    // ---------------- layer 2: o1[32,64] . W2[64] + b2, sigmoid ----------------
    {
        float w2v[4], b1v[4];
#pragma unroll
        for (int n = 0; n < 4; ++n) {
            w2v[n] = W2[n * 16 + lx];
            b1v[n] = b1[n * 16 + lx];
        }
        const float b2v = b2[0];
        float t[2][4];
#pragma unroll
        for (int m = 0; m < 2; ++m)
#pragma unroll
            for (int r = 0; r < 4; ++r) t[m][r] = 0.f;
#pragma unroll
        for (int m = 0; m < 2; ++m)
#pragma unroll
            for (int n = 0; n < 4; ++n)
#pragma unroll
                for (int r = 0; r < 4; ++r) {
                    float v = lrelu(acc1[m][n][r] + b1v[n]);
                    t[m][r] = fmaf(v, w2v[n], t[m][r]);
                }
        // reduce over the 16 lanes (lx) holding different cols of the same row
#pragma unroll
        for (int off = 8; off >= 1; off >>= 1)
#pragma unroll
            for (int m = 0; m < 2; ++m)
#pragma unroll
                for (int r = 0; r < 4; ++r)
                    t[m][r] += __shfl_xor(t[m][r], off, 64);
        if (lx == 0) {
#pragma unroll
            for (int m = 0; m < 2; ++m)
#pragma unroll
                for (int r = 0; r < 4; ++r) {
                    int row = rowBase + m * 16 + lk * 4 + r;
                    if (row < Btot)
                        out[row] = 1.f / (1.f + __expf(-(t[m][r] + b2v)));
                }
        }
    }
}

// ---------------------------------------------------------------------------
// Fallback (round-1 fused kernel) if ws is too small for the split pipeline.
// ---------------------------------------------------------------------------
#define PPB  32
#define NT   256
#define FSTR 260
#define O0STR 132
#define O1STR 68

__device__ __forceinline__ void embed_side_f(
    const float* __restrict__ Z, int idx,
    const float* __restrict__ Wc1, float bc1v,
    const float* __restrict__ Wc2, const float* __restrict__ bc2,
    float sw0, float sw1, float sw2, float sw3,
    int lane, float* dst)
{
    const int k0 = 2 * lane;
    const float* base = Z + (size_t)idx * K_ + k0;
    float2 z0 = *(const float2*)(base + (size_t)0 * N_ * K_);
    float2 z1 = *(const float2*)(base + (size_t)1 * N_ * K_);
    float2 z2 = *(const float2*)(base + (size_t)2 * N_ * K_);
    float2 z3 = *(const float2*)(base + (size_t)3 * N_ * K_);
    float zs0 = z0.x + z1.x + z2.x + z3.x;
    float zs1 = z0.y + z1.y + z2.y + z3.y;
    float2 w0 = *(const float2*)(Wc1 + 0 * K_ + k0);
    float2 w1 = *(const float2*)(Wc1 + 1 * K_ + k0);
    float2 w2 = *(const float2*)(Wc1 + 2 * K_ + k0);
    float2 w3 = *(const float2*)(Wc1 + 3 * K_ + k0);
    float dp = z0.x*w0.x + z0.y*w0.y + z1.x*w1.x + z1.y*w1.y
             + z2.x*w2.x + z2.y*w2.y + z3.x*w3.x + z3.y*w3.y;
#pragma unroll
    for (int off = 32; off >= 1; off >>= 1) dp += __shfl_xor(dp, off, 64);
    float a = lrelu(dp + bc1v);
    float2 c2 = *(const float2*)(Wc2 + k0);
    float2 cb = *(const float2*)(bc2 + k0);
    float l0 = fmaf(a, c2.x, cb.x), l1 = fmaf(a, c2.y, cb.y);
    float m = fmaxf(l0, l1);
#pragma unroll
    for (int off = 32; off >= 1; off >>= 1) m = fmaxf(m, __shfl_xor(m, off, 64));
    float e0 = __expf(l0 - m), e1 = __expf(l1 - m);
    float s = e0 + e1;
#pragma unroll
    for (int off = 32; off >= 1; off >>= 1) s += __shfl_xor(s, off, 64);
    float inv = 1.f / s;
    float e8a = sw0*z0.x + sw1*z1.x + sw2*z2.x + sw3*z3.x;
    float e8b = sw0*z0.y + sw1*z1.y + sw2*z2.y + sw3*z3.y;
    *(float2*)(dst + k0) = make_float2(0.5f*(zs0*(e0*inv)+e8a), 0.5f*(zs1*(e1*inv)+e8b));
}

__global__ __launch_bounds__(NT)
void mf_fused(const float* __restrict__ X, const float* __restrict__ Y,
              const float* __restrict__ x_att, const float* __restrict__ y_att,
              const float* __restrict__ WcX1, const float* __restrict__ bcX1,
              const float* __restrict__ WcX2, const float* __restrict__ bcX2,
              const float* __restrict__ WcY1, const float* __restrict__ bcY1,
              const float* __restrict__ WcY2, const float* __restrict__ bcY2,
              const float* __restrict__ W0, const float* __restrict__ b0,
              const float* __restrict__ W1, const float* __restrict__ b1,
              const float* __restrict__ W2, const float* __restrict__ b2,
              const int* __restrict__ idx0, const int* __restrict__ idx1,
              float* __restrict__ out, int Btot)
{
    __shared__ float pool[PPB * FSTR];
    float* feat = pool;
    const int tid  = threadIdx.x;
    const int lane = tid & 63;
    const int wave = tid >> 6;
    float swx0, swx1, swx2, swx3, swy0, swy1, swy2, swy3;
    {
        float a0 = x_att[0], a1 = x_att[1], a2 = x_att[2], a3 = x_att[3];
        float m = fmaxf(fmaxf(a0, a1), fmaxf(a2, a3));
        float e0 = __expf(a0-m), e1 = __expf(a1-m), e2 = __expf(a2-m), e3 = __expf(a3-m);
        float inv = 1.f / (e0+e1+e2+e3);
        swx0=e0*inv; swx1=e1*inv; swx2=e2*inv; swx3=e3*inv;
        float b0v=y_att[0], b1v=y_att[1], b2v=y_att[2], b3v=y_att[3];
        float my = fmaxf(fmaxf(b0v,b1v), fmaxf(b2v,b3v));
        float f0=__expf(b0v-my), f1=__expf(b1v-my), f2=__expf(b2v-my), f3=__expf(b3v-my);
        float invy = 1.f/(f0+f1+f2+f3);
        swy0=f0*invy; swy1=f1*invy; swy2=f2*invy; swy3=f3*invy;
    }
    const float bcX1v = bcX1[0], bcY1v = bcY1[0];
    const long pair_base = (long)blockIdx.x * PPB;
    for (int pp = 0; pp < PPB/4; ++pp) {
        const int p_local = wave * (PPB/4) + pp;
        const long pair = pair_base + p_local;
        if (pair < Btot) {
            embed_side_f(X, idx0[pair], WcX1, bcX1v, WcX2, bcX2, swx0,swx1,swx2,swx3, lane, feat + p_local*FSTR);
            embed_side_f(Y, idx1[pair], WcY1, bcY1v, WcY2, bcY2, swy0,swy1,swy2,swy3, lane, feat + p_local*FSTR + K_);
        }
    }
    __syncthreads();
    const int jg = tid & 15, pg = tid >> 4;
    float acc[2][8];
#pragma unroll
    for (int p=0;p<2;++p)
#pragma unroll
        for (int j=0;j<8;++j) acc[p][j]=0.f;
    const float* frow0 = feat + (pg*2+0)*FSTR;
    const float* frow1 = feat + (pg*2+1)*FSTR;
    for (int i = 0; i < 2*K_; i += 4) {
        float fav[4], fbv[4];
        *(float4*)fav = *(const float4*)(frow0+i);
        *(float4*)fbv = *(const float4*)(frow1+i);
#pragma unroll
        for (int u=0;u<4;++u) {
            float wv[8];
            *(float4*)(wv)   = *(const float4*)(W0 + (i+u)*K_ + jg*8);
            *(float4*)(wv+4) = *(const float4*)(W0 + (i+u)*K_ + jg*8 + 4);
#pragma unroll
            for (int j=0;j<8;++j) {
                acc[0][j] = fmaf(fav[u], wv[j], acc[0][j]);
                acc[1][j] = fmaf(fbv[u], wv[j], acc[1][j]);
            }
        }
    }
    __syncthreads();
    float* o0 = pool;
    {
        float bv[8];
        *(float4*)bv     = *(const float4*)(b0 + jg*8);
        *(float4*)(bv+4) = *(const float4*)(b0 + jg*8 + 4);
#pragma unroll
        for (int p=0;p<2;++p) {
            float v[8];
#pragma unroll
            for (int j=0;j<8;++j) v[j] = lrelu(acc[p][j] + bv[j]);
            *(float4*)(o0 + (pg*2+p)*O0STR + jg*8)     = *(float4*)v;
            *(float4*)(o0 + (pg*2+p)*O0STR + jg*8 + 4) = *(float4*)(v+4);
        }
    }
    __syncthreads();
    float acc1[2][4];
#pragma unroll
    for (int p=0;p<2;++p)
#pragma unroll
        for (int j=0;j<4;++j) acc1[p][j]=0.f;
    const float* r0 = o0 + (pg*2+0)*O0STR;
    const float* r1 = o0 + (pg*2+1)*O0STR;
    for (int i = 0; i < K_; i += 4) {
        float fav[4], fbv[4];
        *(float4*)fav = *(const float4*)(r0+i);
        *(float4*)fbv = *(const float4*)(r1+i);
#pragma unroll
        for (int u=0;u<4;++u) {
            float wv[4];
            *(float4*)wv = *(const float4*)(W1 + (i+u)*(K_/2) + jg*4);
#pragma unroll
            for (int j=0;j<4;++j) {
                acc1[0][j] = fmaf(fav[u], wv[j], acc1[0][j]);
                acc1[1][j] = fmaf(fbv[u], wv[j], acc1[1][j]);
            }
        }
    }
    float* o1 = pool + PPB*O0STR;
    {
        float bv[4];
        *(float4*)bv = *(const float4*)(b1 + jg*4);
#pragma unroll
        for (int p=0;p<2;++p) {
            float v[4];
#pragma unroll
            for (int j=0;j<4;++j) v[j] = lrelu(acc1[p][j] + bv[j]);
            *(float4*)(o1 + (pg*2+p)*O1STR + jg*4) = *(float4*)v;
        }
    }
    __syncthreads();
    {
        const int p = tid >> 3, part = tid & 7;
        const float* r = o1 + p*O1STR + part*8;
        float rv[8], wv[8];
        *(float4*)rv     = *(const float4*)(r);
        *(float4*)(rv+4) = *(const float4*)(r+4);
        *(float4*)wv     = *(const float4*)(W2 + part*8);
        *(float4*)(wv+4) = *(const float4*)(W2 + part*8 + 4);
        float d = 0.f;
#pragma unroll
        for (int j=0;j<8;++j) d = fmaf(rv[j], wv[j], d);
        d += __shfl_xor(d, 1, 64);
        d += __shfl_xor(d, 2, 64);
        d += __shfl_xor(d, 4, 64);
        if (part == 0) {
            const long pair = pair_base + p;
            if (pair < Btot) out[pair] = 1.f / (1.f + __expf(-(d + b2[0])));
        }
    }
}

// ---------------------------------------------------------------------------
extern "C" void kernel_launch(void* const* d_in, const int* in_sizes, int n_in,
                              void* d_out, int out_size, void* d_ws, size_t ws_size,
                              hipStream_t stream) {
    const float* X    = (const float*)d_in[0];
    const float* Y    = (const float*)d_in[1];
    const float* xatt = (const float*)d_in[2];
    const float* yatt = (const float*)d_in[3];
    const float* WcX1 = (const float*)d_in[4];
    const float* bcX1 = (const float*)d_in[5];
    const float* WcX2 = (const float*)d_in[6];
    const float* bcX2 = (const float*)d_in[7];
    const float* WcY1 = (const float*)d_in[8];
    const float* bcY1 = (const float*)d_in[9];
    const float* WcY2 = (const float*)d_in[10];
    const float* bcY2 = (const float*)d_in[11];
    const float* W0   = (const float*)d_in[12];
    const float* b0   = (const float*)d_in[13];
    const float* W1   = (const float*)d_in[14];
    const float* b1   = (const float*)d_in[15];
    const float* W2   = (const float*)d_in[16];
    const float* b2   = (const float*)d_in[17];
    const int* idx0   = (const int*)d_in[18];
    const int* idx1   = (const int*)d_in[19];
    float* out        = (float*)d_out;

    const int Btot = in_sizes[18];
    const int dblocks = (Btot + 127) / 128;
    // ws layout: [0,64K) W0T | [64K,80K) W1T | [1M,5M) Xemb | [5M,9M) Yemb
    const size_t need = (9u << 20);

    if (ws_size >= need) {
        unsigned short* W0T  = (unsigned short*)d_ws;
        unsigned short* W1T  = (unsigned short*)((char*)d_ws + 65536);
        unsigned short* Xemb = (unsigned short*)((char*)d_ws + (1u << 20));
        unsigned short* Yemb = (unsigned short*)((char*)d_ws + (5u << 20));

        convert_w<<<(128*256 + 64*128 + 255) / 256, 256, 0, stream>>>(W0, W1, W0T, W1T);
        node_embed<<<N_ / 4, 256, 0, stream>>>(
            X, Y, xatt, yatt, WcX1, bcX1, WcX2, bcX2,
            WcY1, bcY1, WcY2, bcY2, Xemb, Yemb);
        decoder_kernel<<<dblocks, 256, 0, stream>>>(
            Xemb, Yemb, W0T, W1T, b0, b1, W2, b2, idx0, idx1, out, Btot);
    } else {
        mf_fused<<<(Btot + PPB - 1) / PPB, NT, 0, stream>>>(
            X, Y, xatt, yatt, WcX1, bcX1, WcX2, bcX2,
            WcY1, bcY1, WcY2, bcY2, W0, b0, W1, b1, W2, b2,
            idx0, idx1, out, Btot);
    }
}

// Round 6
// 180.548 us; speedup vs baseline: 2.6939x; 1.0890x over previous
//
#include <hip/hip_runtime.h>
#include <hip/hip_bf16.h>

#define S_   4
#define N_   16384
#define K_   128
#define CONV_BLOCKS 160   // (128*256 + 64*128) / 256

typedef __attribute__((ext_vector_type(8))) short short8v;   // 8 bf16 = 4 VGPR
typedef __attribute__((ext_vector_type(4))) float f32x4;

__device__ __forceinline__ float lrelu(float x) { return x > 0.f ? x : 0.01f * x; }

__device__ __forceinline__ unsigned short f2bf(float f) {
    union { float f; unsigned u; } v; v.f = f;
    unsigned r = v.u + 0x7fff + ((v.u >> 16) & 1);   // round-to-nearest-even
    return (unsigned short)(r >> 16);
}

// ---------------------------------------------------------------------------
// Kernel 1: fused {weight convert + node embedding}.
// Blocks [0, CONV_BLOCKS): W0 [256,128] f32 -> W0T [128][256] bf16 (transposed)
//                          W1 [128,64]  f32 -> W1T [64][128]  bf16 (transposed)
// Blocks [CONV_BLOCKS, ...): node embedding, one wave per node
//   (lanes 0-31 side X, 32-63 side Y), coalesced sequential reads, writes
//   Xemb[N][128] / Yemb[N][128] bf16 (8.4 MB total -> L2/L3-resident).
// Embedding is a pure function of the node -> computed N times, not B times.
// ---------------------------------------------------------------------------
__global__ __launch_bounds__(256)
void embed_convert(const float* __restrict__ X, const float* __restrict__ Y,
                   const float* __restrict__ x_att, const float* __restrict__ y_att,
                   const float* __restrict__ WcX1, const float* __restrict__ bcX1,
                   const float* __restrict__ WcX2, const float* __restrict__ bcX2,
                   const float* __restrict__ WcY1, const float* __restrict__ bcY1,
                   const float* __restrict__ WcY2, const float* __restrict__ bcY2,
                   const float* __restrict__ W0, const float* __restrict__ W1,
                   unsigned short* __restrict__ W0T, unsigned short* __restrict__ W1T,
                   unsigned short* __restrict__ Xemb, unsigned short* __restrict__ Yemb)
{
    if (blockIdx.x < CONV_BLOCKS) {
        int t = blockIdx.x * 256 + threadIdx.x;
        if (t < 128 * 256) {                 // W0T[n][k] = W0[k][n]
            int n = t >> 8, k = t & 255;
            W0T[t] = f2bf(W0[k * 128 + n]);
        }
        t -= 128 * 256;
        if (t >= 0 && t < 64 * 128) {        // W1T[n][k] = W1[k][n]
            int n = t >> 7, k = t & 127;
            W1T[t] = f2bf(W1[k * 64 + n]);
        }
        return;
    }

    const int node = (blockIdx.x - CONV_BLOCKS) * 4 + (threadIdx.x >> 6);
    if (node >= N_) return;
    const int lane = threadIdx.x & 63;
    const int half = lane >> 5;          // 0 = X side, 1 = Y side
    const int sl   = lane & 31;
    const int k0   = sl * 4;

    const float* Z    = half ? Y    : X;
    const float* Wc1  = half ? WcY1 : WcX1;
    const float* Wc2  = half ? WcY2 : WcX2;
    const float* bc2h = half ? bcY2 : bcX2;
    const float  bc1v = half ? bcY1[0] : bcX1[0];
    const float* attv = half ? y_att : x_att;
    unsigned short* dst = half ? Yemb : Xemb;

    // view softmax (4 scalars)
    float a0 = attv[0], a1 = attv[1], a2 = attv[2], a3 = attv[3];
    float am = fmaxf(fmaxf(a0, a1), fmaxf(a2, a3));
    float sw0 = __expf(a0 - am), sw1 = __expf(a1 - am),
          sw2 = __expf(a2 - am), sw3 = __expf(a3 - am);
    float swinv = 1.f / (sw0 + sw1 + sw2 + sw3);
    sw0 *= swinv; sw1 *= swinv; sw2 *= swinv; sw3 *= swinv;

    // sequential coalesced reads: 4 view rows of this node (+ Wc1 rows)
    float4 z0 = *(const float4*)(Z + ((size_t)0 * N_ + node) * K_ + k0);
    float4 z1 = *(const float4*)(Z + ((size_t)1 * N_ + node) * K_ + k0);
    float4 z2 = *(const float4*)(Z + ((size_t)2 * N_ + node) * K_ + k0);
    float4 z3 = *(const float4*)(Z + ((size_t)3 * N_ + node) * K_ + k0);
    float4 w0 = *(const float4*)(Wc1 + 0 * K_ + k0);
    float4 w1 = *(const float4*)(Wc1 + 1 * K_ + k0);
    float4 w2 = *(const float4*)(Wc1 + 2 * K_ + k0);
    float4 w3 = *(const float4*)(Wc1 + 3 * K_ + k0);
    float4 c2 = *(const float4*)(Wc2 + k0);
    float4 cb = *(const float4*)(bc2h + k0);

    float4 zs;
    zs.x = z0.x + z1.x + z2.x + z3.x;
    zs.y = z0.y + z1.y + z2.y + z3.y;
    zs.z = z0.z + z1.z + z2.z + z3.z;
    zs.w = z0.w + z1.w + z2.w + z3.w;

    // dp = dot(Zcat, Wc1), 32-lane butterfly within each half
    float dp = z0.x*w0.x + z0.y*w0.y + z0.z*w0.z + z0.w*w0.w
             + z1.x*w1.x + z1.y*w1.y + z1.z*w1.z + z1.w*w1.w
             + z2.x*w2.x + z2.y*w2.y + z2.z*w2.z + z2.w*w2.w
             + z3.x*w3.x + z3.y*w3.y + z3.z*w3.z + z3.w*w3.w;
#pragma unroll
    for (int off = 16; off >= 1; off >>= 1) dp += __shfl_xor(dp, off, 64);

    float a = lrelu(dp + bc1v);

    // attention logits over K, softmax within 32-lane half
    float l0 = fmaf(a, c2.x, cb.x), l1 = fmaf(a, c2.y, cb.y);
    float l2 = fmaf(a, c2.z, cb.z), l3 = fmaf(a, c2.w, cb.w);
    float m = fmaxf(fmaxf(l0, l1), fmaxf(l2, l3));
#pragma unroll
    for (int off = 16; off >= 1; off >>= 1) m = fmaxf(m, __shfl_xor(m, off, 64));
    float e0 = __expf(l0 - m), e1 = __expf(l1 - m),
          e2 = __expf(l2 - m), e3 = __expf(l3 - m);
    float s = e0 + e1 + e2 + e3;
#pragma unroll
    for (int off = 16; off >= 1; off >>= 1) s += __shfl_xor(s, off, 64);
    float inv = 1.f / s;

    float o0v = 0.5f * (zs.x * (e0 * inv) + (sw0*z0.x + sw1*z1.x + sw2*z2.x + sw3*z3.x));
    float o1v = 0.5f * (zs.y * (e1 * inv) + (sw0*z0.y + sw1*z1.y + sw2*z2.y + sw3*z3.y));
    float o2v = 0.5f * (zs.z * (e2 * inv) + (sw0*z0.z + sw1*z1.z + sw2*z2.z + sw3*z3.z));
    float o3v = 0.5f * (zs.w * (e3 * inv) + (sw0*z0.w + sw1*z1.w + sw2*z2.w + sw3*z3.w));

    ushort4 p;
    p.x = f2bf(o0v); p.y = f2bf(o1v); p.z = f2bf(o2v); p.w = f2bf(o3v);
    *(ushort4*)(dst + (size_t)node * K_ + k0) = p;
}

// ---------------------------------------------------------------------------
// Kernel 2: MFMA decoder. 128 rows/block, 4 waves, 32 rows/wave.
// R5 changes vs R4 (latency fix; math identical):
//  - ALL 16 A-gather fragments prefetched before any MFMA (one stall point)
//  - B-fragments loaded as one 8-load group per kk-step (vs per-MFMA JIT)
//  - bias/W2 scalars hoisted to kernel start
//  - __launch_bounds__(256,4): VGPR<=128 -> 4 blocks/CU (16 waves/CU TLP)
// Waves fully independent: no __syncthreads.
// ---------------------------------------------------------------------------
__global__ __launch_bounds__(256, 4)
void decoder_kernel(const unsigned short* __restrict__ Xemb,
                    const unsigned short* __restrict__ Yemb,
                    const unsigned short* __restrict__ W0T,
                    const unsigned short* __restrict__ W1T,
                    const float* __restrict__ b0, const float* __restrict__ b1,
                    const float* __restrict__ W2, const float* __restrict__ b2,
                    const int* __restrict__ idx0, const int* __restrict__ idx1,
                    float* __restrict__ out, int Btot)
{
    __shared__ unsigned short o0[128 * 136];   // 136 = 128 + 8 pad (272B stride)

    const int wave = threadIdx.x >> 6;
    const int lane = threadIdx.x & 63;
    const int lx   = lane & 15;     // row (A) / col (B) index inside tile
    const int lk   = lane >> 4;     // k-group: k = lk*8 .. +7
    const int rowBase = blockIdx.x * 128 + wave * 32;

    int r0 = rowBase + lx;       if (r0 >= Btot) r0 = Btot - 1;
    int r1 = rowBase + 16 + lx;  if (r1 >= Btot) r1 = Btot - 1;
    const unsigned short* xb0 = Xemb + (size_t)idx0[r0] * K_ + lk * 8;
    const unsigned short* xb1 = Xemb + (size_t)idx0[r1] * K_ + lk * 8;
    const unsigned short* yb0 = Yemb + (size_t)idx1[r0] * K_ + lk * 8;
    const unsigned short* yb1 = Yemb + (size_t)idx1[r1] * K_ + lk * 8;

    // hoisted scalars (issued before the MFMA phase)
    float b0v[8], b1v[4], w2v[4];
#pragma unroll
    for (int n = 0; n < 8; ++n) b0v[n] = b0[n * 16 + lx];
#pragma unroll
    for (int n = 0; n < 4; ++n) { b1v[n] = b1[n * 16 + lx]; w2v[n] = W2[n * 16 + lx]; }
    const float b2v = b2[0];

    // ---- A prefetch: all 16 fragments (cols 0..127 = X, 128..255 = Y) ----
    short8v A0[8], A1[8];
#pragma unroll
    for (int kk = 0; kk < 4; ++kk) {
        A0[kk]     = *(const short8v*)(xb0 + kk * 32);
        A1[kk]     = *(const short8v*)(xb1 + kk * 32);
        A0[kk + 4] = *(const short8v*)(yb0 + kk * 32);
        A1[kk + 4] = *(const short8v*)(yb1 + kk * 32);
    }

    // ---------------- layer 0: [32,256] @ [256,128] ----------------
    f32x4 acc[2][8];
#pragma unroll
    for (int m = 0; m < 2; ++m)
#pragma unroll
        for (int n = 0; n < 8; ++n) acc[m][n] = (f32x4)0.f;

#pragma unroll
    for (int kk = 0; kk < 8; ++kk) {
        const int koff = kk * 32 + lk * 8;
        short8v Bv[8];
#pragma unroll
        for (int n = 0; n < 8; ++n)
            Bv[n] = *(const short8v*)(W0T + (size_t)(n * 16 + lx) * 256 + koff);
#pragma unroll
        for (int n = 0; n < 8; ++n) {
            acc[0][n] = __builtin_amdgcn_mfma_f32_16x16x32_bf16(A0[kk], Bv[n], acc[0][n], 0, 0, 0);
            acc[1][n] = __builtin_amdgcn_mfma_f32_16x16x32_bf16(A1[kk], Bv[n], acc[1][n], 0, 0, 0);
        }
    }

    // epilogue: +b0, lrelu, bf16 -> LDS o0 (C/D map: col=lane&15, row=(lane>>4)*4+r)
#pragma unroll
    for (int m = 0; m < 2; ++m)
#pragma unroll
        for (int n = 0; n < 8; ++n)
#pragma unroll
            for (int r = 0; r < 4; ++r) {
                float v = lrelu(acc[m][n][r] + b0v[n]);
                int row = wave * 32 + m * 16 + lk * 4 + r;
                o0[row * 136 + n * 16 + lx] = f2bf(v);
            }
    // wave reads only its own writes; compiler inserts lgkmcnt waits.

    // ---------------- layer 1: [32,128] @ [128,64] ----------------
    // A prefetch from LDS: all 8 fragments grouped
    short8v La0[4], La1[4];
#pragma unroll
    for (int kk = 0; kk < 4; ++kk) {
        const int koff = kk * 32 + lk * 8;
        La0[kk] = *(const short8v*)(&o0[(wave * 32 + lx) * 136 + koff]);
        La1[kk] = *(const short8v*)(&o0[(wave * 32 + 16 + lx) * 136 + koff]);
    }

    f32x4 acc1[2][4];
#pragma unroll
    for (int m = 0; m < 2; ++m)
#pragma unroll
        for (int n = 0; n < 4; ++n) acc1[m][n] = (f32x4)0.f;

#pragma unroll
    for (int kk = 0; kk < 4; ++kk) {
        const int koff = kk * 32 + lk * 8;
        short8v Bv1[4];
#pragma unroll
        for (int n = 0; n < 4; ++n)
            Bv1[n] = *(const short8v*)(W1T + (size_t)(n * 16 + lx) * 128 + koff);
#pragma unroll
        for (int n = 0; n < 4; ++n) {
            acc1[0][n] = __builtin_amdgcn_mfma_f32_16x16x32_bf16(La0[kk], Bv1[n], acc1[0][n], 0, 0, 0);
            acc1[1][n] = __builtin_amdgcn_mfma_f32_16x16x32_bf16(La1[kk], Bv1[n], acc1[1][n], 0, 0, 0);
        }
    }

    // ---------------- layer 2: o1[32,64] . W2[64] + b2, sigmoid ----------------
    {
        float t[2][4];
#pragma unroll
        for (int m = 0; m < 2; ++m)
#pragma unroll
            for (int r = 0; r < 4; ++r) t[m][r] = 0.f;
#pragma unroll
        for (int m = 0; m < 2; ++m)
#pragma unroll
            for (int n = 0; n < 4; ++n)
#pragma unroll
                for (int r = 0; r < 4; ++r) {
                    float v = lrelu(acc1[m][n][r] + b1v[n]);
                    t[m][r] = fmaf(v, w2v[n], t[m][r]);
                }
        // reduce over the 16 lanes (lx) holding different cols of the same row
#pragma unroll
        for (int off = 8; off >= 1; off >>= 1)
#pragma unroll
            for (int m = 0; m < 2; ++m)
#pragma unroll
                for (int r = 0; r < 4; ++r)
                    t[m][r] += __shfl_xor(t[m][r], off, 64);
        if (lx == 0) {
#pragma unroll
            for (int m = 0; m < 2; ++m)
#pragma unroll
                for (int r = 0; r < 4; ++r) {
                    int row = rowBase + m * 16 + lk * 4 + r;
                    if (row < Btot)
                        out[row] = 1.f / (1.f + __expf(-(t[m][r] + b2v)));
                }
        }
    }
}

// ---------------------------------------------------------------------------
// Fallback (round-1 fused kernel) if ws is too small for the split pipeline.
// ---------------------------------------------------------------------------
#define PPB  32
#define NT   256
#define FSTR 260
#define O0STR 132
#define O1STR 68

__device__ __forceinline__ void embed_side_f(
    const float* __restrict__ Z, int idx,
    const float* __restrict__ Wc1, float bc1v,
    const float* __restrict__ Wc2, const float* __restrict__ bc2,
    float sw0, float sw1, float sw2, float sw3,
    int lane, float* dst)
{
    const int k0 = 2 * lane;
    const float* base = Z + (size_t)idx * K_ + k0;
    float2 z0 = *(const float2*)(base + (size_t)0 * N_ * K_);
    float2 z1 = *(const float2*)(base + (size_t)1 * N_ * K_);
    float2 z2 = *(const float2*)(base + (size_t)2 * N_ * K_);
    float2 z3 = *(const float2*)(base + (size_t)3 * N_ * K_);
    float zs0 = z0.x + z1.x + z2.x + z3.x;
    float zs1 = z0.y + z1.y + z2.y + z3.y;
    float2 w0 = *(const float2*)(Wc1 + 0 * K_ + k0);
    float2 w1 = *(const float2*)(Wc1 + 1 * K_ + k0);
    float2 w2 = *(const float2*)(Wc1 + 2 * K_ + k0);
    float2 w3 = *(const float2*)(Wc1 + 3 * K_ + k0);
    float dp = z0.x*w0.x + z0.y*w0.y + z1.x*w1.x + z1.y*w1.y
             + z2.x*w2.x + z2.y*w2.y + z3.x*w3.x + z3.y*w3.y;
#pragma unroll
    for (int off = 32; off >= 1; off >>= 1) dp += __shfl_xor(dp, off, 64);
    float a = lrelu(dp + bc1v);
    float2 c2 = *(const float2*)(Wc2 + k0);
    float2 cb = *(const float2*)(bc2 + k0);
    float l0 = fmaf(a, c2.x, cb.x), l1 = fmaf(a, c2.y, cb.y);
    float m = fmaxf(l0, l1);
#pragma unroll
    for (int off = 32; off >= 1; off >>= 1) m = fmaxf(m, __shfl_xor(m, off, 64));
    float e0 = __expf(l0 - m), e1 = __expf(l1 - m);
    float s = e0 + e1;
#pragma unroll
    for (int off = 32; off >= 1; off >>= 1) s += __shfl_xor(s, off, 64);
    float inv = 1.f / s;
    float e8a = sw0*z0.x + sw1*z1.x + sw2*z2.x + sw3*z3.x;
    float e8b = sw0*z0.y + sw1*z1.y + sw2*z2.y + sw3*z3.y;
    *(float2*)(dst + k0) = make_float2(0.5f*(zs0*(e0*inv)+e8a), 0.5f*(zs1*(e1*inv)+e8b));
}

__global__ __launch_bounds__(NT)
void mf_fused(const float* __restrict__ X, const float* __restrict__ Y,
              const float* __restrict__ x_att, const float* __restrict__ y_att,
              const float* __restrict__ WcX1, const float* __restrict__ bcX1,
              const float* __restrict__ WcX2, const float* __restrict__ bcX2,
              const float* __restrict__ WcY1, const float* __restrict__ bcY1,
              const float* __restrict__ WcY2, const float* __restrict__ bcY2,
              const float* __restrict__ W0, const float* __restrict__ b0,
              const float* __restrict__ W1, const float* __restrict__ b1,
              const float* __restrict__ W2, const float* __restrict__ b2,
              const int* __restrict__ idx0, const int* __restrict__ idx1,
              float* __restrict__ out, int Btot)
{
    __shared__ float pool[PPB * FSTR];
    float* feat = pool;
    const int tid  = threadIdx.x;
    const int lane = tid & 63;
    const int wave = tid >> 6;
    float swx0, swx1, swx2, swx3, swy0, swy1, swy2, swy3;
    {
        float a0 = x_att[0], a1 = x_att[1], a2 = x_att[2], a3 = x_att[3];
        float m = fmaxf(fmaxf(a0, a1), fmaxf(a2, a3));
        float e0 = __expf(a0-m), e1 = __expf(a1-m), e2 = __expf(a2-m), e3 = __expf(a3-m);
        float inv = 1.f / (e0+e1+e2+e3);
        swx0=e0*inv; swx1=e1*inv; swx2=e2*inv; swx3=e3*inv;
        float b0v=y_att[0], b1v=y_att[1], b2v=y_att[2], b3v=y_att[3];
        float my = fmaxf(fmaxf(b0v,b1v), fmaxf(b2v,b3v));
        float f0=__expf(b0v-my), f1=__expf(b1v-my), f2=__expf(b2v-my), f3=__expf(b3v-my);
        float invy = 1.f/(f0+f1+f2+f3);
        swy0=f0*invy; swy1=f1*invy; swy2=f2*invy; swy3=f3*invy;
    }
    const float bcX1v = bcX1[0], bcY1v = bcY1[0];
    const long pair_base = (long)blockIdx.x * PPB;
    for (int pp = 0; pp < PPB/4; ++pp) {
        const int p_local = wave * (PPB/4) + pp;
        const long pair = pair_base + p_local;
        if (pair < Btot) {
            embed_side_f(X, idx0[pair], WcX1, bcX1v, WcX2, bcX2, swx0,swx1,swx2,swx3, lane, feat + p_local*FSTR);
            embed_side_f(Y, idx1[pair], WcY1, bcY1v, WcY2, bcY2, swy0,swy1,swy2,swy3, lane, feat + p_local*FSTR + K_);
        }
    }
    __syncthreads();
    const int jg = tid & 15, pg = tid >> 4;
    float acc[2][8];
#pragma unroll
    for (int p=0;p<2;++p)
#pragma unroll
        for (int j=0;j<8;++j) acc[p][j]=0.f;
    const float* frow0 = feat + (pg*2+0)*FSTR;
    const float* frow1 = feat + (pg*2+1)*FSTR;
    for (int i = 0; i < 2*K_; i += 4) {
        float fav[4], fbv[4];
        *(float4*)fav = *(const float4*)(frow0+i);
        *(float4*)fbv = *(const float4*)(frow1+i);
#pragma unroll
        for (int u=0;u<4;++u) {
            float wv[8];
            *(float4*)(wv)   = *(const float4*)(W0 + (i+u)*K_ + jg*8);
            *(float4*)(wv+4) = *(const float4*)(W0 + (i+u)*K_ + jg*8 + 4);
#pragma unroll
            for (int j=0;j<8;++j) {
                acc[0][j] = fmaf(fav[u], wv[j], acc[0][j]);
                acc[1][j] = fmaf(fbv[u], wv[j], acc[1][j]);
            }
        }
    }
    __syncthreads();
    float* o0 = pool;
    {
        float bv[8];
        *(float4*)bv     = *(const float4*)(b0 + jg*8);
        *(float4*)(bv+4) = *(const float4*)(b0 + jg*8 + 4);
#pragma unroll
        for (int p=0;p<2;++p) {
            float v[8];
#pragma unroll
            for (int j=0;j<8;++j) v[j] = lrelu(acc[p][j] + bv[j]);
            *(float4*)(o0 + (pg*2+p)*O0STR + jg*8)     = *(float4*)v;
            *(float4*)(o0 + (pg*2+p)*O0STR + jg*8 + 4) = *(float4*)(v+4);
        }
    }
    __syncthreads();
    float acc1[2][4];
#pragma unroll
    for (int p=0;p<2;++p)
#pragma unroll
        for (int j=0;j<4;++j) acc1[p][j]=0.f;
    const float* r0 = o0 + (pg*2+0)*O0STR;
    const float* r1 = o0 + (pg*2+1)*O0STR;
    for (int i = 0; i < K_; i += 4) {
        float fav[4], fbv[4];
        *(float4*)fav = *(const float4*)(r0+i);
        *(float4*)fbv = *(const float4*)(r1+i);
#pragma unroll
        for (int u=0;u<4;++u) {
            float wv[4];
            *(float4*)wv = *(const float4*)(W1 + (i+u)*(K_/2) + jg*4);
#pragma unroll
            for (int j=0;j<4;++j) {
                acc1[0][j] = fmaf(fav[u], wv[j], acc1[0][j]);
                acc1[1][j] = fmaf(fbv[u], wv[j], acc1[1][j]);
            }
        }
    }
    float* o1 = pool + PPB*O0STR;
    {
        float bv[4];
        *(float4*)bv = *(const float4*)(b1 + jg*4);
#pragma unroll
        for (int p=0;p<2;++p) {
            float v[4];
#pragma unroll
            for (int j=0;j<4;++j) v[j] = lrelu(acc1[p][j] + bv[j]);
            *(float4*)(o1 + (pg*2+p)*O1STR + jg*4) = *(float4*)v;
        }
    }
    __syncthreads();
    {
        const int p = tid >> 3, part = tid & 7;
        const float* r = o1 + p*O1STR + part*8;
        float rv[8], wv[8];
        *(float4*)rv     = *(const float4*)(r);
        *(float4*)(rv+4) = *(const float4*)(r+4);
        *(float4*)wv     = *(const float4*)(W2 + part*8);
        *(float4*)(wv+4) = *(const float4*)(W2 + part*8 + 4);
        float d = 0.f;
#pragma unroll
        for (int j=0;j<8;++j) d = fmaf(rv[j], wv[j], d);
        d += __shfl_xor(d, 1, 64);
        d += __shfl_xor(d, 2, 64);
        d += __shfl_xor(d, 4, 64);
        if (part == 0) {
            const long pair = pair_base + p;
            if (pair < Btot) out[pair] = 1.f / (1.f + __expf(-(d + b2[0])));
        }
    }
}

// ---------------------------------------------------------------------------
extern "C" void kernel_launch(void* const* d_in, const int* in_sizes, int n_in,
                              void* d_out, int out_size, void* d_ws, size_t ws_size,
                              hipStream_t stream) {
    const float* X    = (const float*)d_in[0];
    const float* Y    = (const float*)d_in[1];
    const float* xatt = (const float*)d_in[2];
    const float* yatt = (const float*)d_in[3];
    const float* WcX1 = (const float*)d_in[4];
    const float* bcX1 = (const float*)d_in[5];
    const float* WcX2 = (const float*)d_in[6];
    const float* bcX2 = (const float*)d_in[7];
    const float* WcY1 = (const float*)d_in[8];
    const float* bcY1 = (const float*)d_in[9];
    const float* WcY2 = (const float*)d_in[10];
    const float* bcY2 = (const float*)d_in[11];
    const float* W0   = (const float*)d_in[12];
    const float* b0   = (const float*)d_in[13];
    const float* W1   = (const float*)d_in[14];
    const float* b1   = (const float*)d_in[15];
    const float* W2   = (const float*)d_in[16];
    const float* b2   = (const float*)d_in[17];
    const int* idx0   = (const int*)d_in[18];
    const int* idx1   = (const int*)d_in[19];
    float* out        = (float*)d_out;

    const int Btot = in_sizes[18];
    const int dblocks = (Btot + 127) / 128;
    // ws layout: [0,64K) W0T | [64K,80K) W1T | [1M,5M) Xemb | [5M,9M) Yemb
    const size_t need = (9u << 20);

    if (ws_size >= need) {
        unsigned short* W0T  = (unsigned short*)d_ws;
        unsigned short* W1T  = (unsigned short*)((char*)d_ws + 65536);
        unsigned short* Xemb = (unsigned short*)((char*)d_ws + (1u << 20));
        unsigned short* Yemb = (unsigned short*)((char*)d_ws + (5u << 20));

        embed_convert<<<CONV_BLOCKS + N_ / 4, 256, 0, stream>>>(
            X, Y, xatt, yatt, WcX1, bcX1, WcX2, bcX2,
            WcY1, bcY1, WcY2, bcY2, W0, W1, W0T, W1T, Xemb, Yemb);
        decoder_kernel<<<dblocks, 256, 0, stream>>>(
            Xemb, Yemb, W0T, W1T, b0, b1, W2, b2, idx0, idx1, out, Btot);
    } else {
        mf_fused<<<(Btot + PPB - 1) / PPB, NT, 0, stream>>>(
            X, Y, xatt, yatt, WcX1, bcX1, WcX2, bcX2,
            WcY1, bcY1, WcY2, bcY2, W0, b0, W1, b1, W2, b2,
            idx0, idx1, out, Btot);
    }
}

// Round 9
// 159.372 us; speedup vs baseline: 3.0518x; 1.1329x over previous
//
#include <hip/hip_runtime.h>
#include <hip/hip_bf16.h>

#define S_   4
#define N_   16384
#define K_   128
#define LDSTRIDE 272                    // W0 LDS-image row stride (elems): 544B -> even bank spread
#define W0IMG_ELEMS (128 * LDSTRIDE)    // 34816 elems = 69632 B
#define HALF_ELEMS  (64 * LDSTRIDE)     // 17408 elems per staged half
#define SCR_STRIDE  40                  // per-wave transpose scratch row stride (elems)
#define CONV_ELEMS  (W0IMG_ELEMS + 64 * 128)   // W0 image + W1T
#define CONV_BLOCKS ((CONV_ELEMS + 255) / 256) // 168

typedef __attribute__((ext_vector_type(8))) short short8v;   // 8 bf16 = 4 VGPR
typedef __attribute__((ext_vector_type(4))) float f32x4;

__device__ __forceinline__ float lrelu(float x) { return x > 0.f ? x : 0.01f * x; }

__device__ __forceinline__ unsigned short f2bf(float f) {
    union { float f; unsigned u; } v; v.f = f;
    unsigned r = v.u + 0x7fff + ((v.u >> 16) & 1);   // round-to-nearest-even
    return (unsigned short)(r >> 16);
}

// ---------------------------------------------------------------------------
// Kernel 1: fused {weight convert + node embedding}.
// Blocks [0, CONV_BLOCKS):
//   W0 [256,128] f32 -> W0img [128][LDSTRIDE] bf16: W0img[n][k] = W0[k][n]
//     (transposed, padded rows; byte-identical image of the decoder's LDS)
//   W1 [128,64]  f32 -> W1T [64][128] bf16 (transposed)
// Blocks [CONV_BLOCKS, ...): node embedding, one wave per node
//   (lanes 0-31 side X, 32-63 side Y), coalesced sequential reads ->
//   Xemb[N][128], Yemb[N][128] bf16 (8.4 MB, L2/L3-resident).
// Embedding is a pure function of the node -> computed N times, not B times.
// ---------------------------------------------------------------------------
__global__ __launch_bounds__(256)
void embed_convert(const float* __restrict__ X, const float* __restrict__ Y,
                   const float* __restrict__ x_att, const float* __restrict__ y_att,
                   const float* __restrict__ WcX1, const float* __restrict__ bcX1,
                   const float* __restrict__ WcX2, const float* __restrict__ bcX2,
                   const float* __restrict__ WcY1, const float* __restrict__ bcY1,
                   const float* __restrict__ WcY2, const float* __restrict__ bcY2,
                   const float* __restrict__ W0, const float* __restrict__ W1,
                   unsigned short* __restrict__ W0img, unsigned short* __restrict__ W1T,
                   unsigned short* __restrict__ Xemb, unsigned short* __restrict__ Yemb)
{
    if (blockIdx.x < CONV_BLOCKS) {
        int t = blockIdx.x * 256 + threadIdx.x;
        if (t < W0IMG_ELEMS) {               // W0img[row][col] = W0[col][row]
            int row = t / LDSTRIDE, col = t % LDSTRIDE;
            W0img[t] = (col < 256) ? f2bf(W0[col * 128 + row]) : (unsigned short)0;
        }
        t -= W0IMG_ELEMS;
        if (t >= 0 && t < 64 * 128) {        // W1T[n][k] = W1[k][n]
            int n = t >> 7, k = t & 127;
            W1T[t] = f2bf(W1[k * 64 + n]);
        }
        return;
    }

    const int node = (blockIdx.x - CONV_BLOCKS) * 4 + (threadIdx.x >> 6);
    if (node >= N_) return;
    const int lane = threadIdx.x & 63;
    const int half = lane >> 5;          // 0 = X side, 1 = Y side
    const int sl   = lane & 31;
    const int k0   = sl * 4;

    const float* Z    = half ? Y    : X;
    const float* Wc1  = half ? WcY1 : WcX1;
    const float* Wc2  = half ? WcY2 : WcX2;
    const float* bc2h = half ? bcY2 : bcX2;
    const float  bc1v = half ? bcY1[0] : bcX1[0];
    const float* attv = half ? y_att : x_att;
    unsigned short* dst = half ? Yemb : Xemb;

    // view softmax (4 scalars)
    float a0 = attv[0], a1 = attv[1], a2 = attv[2], a3 = attv[3];
    float am = fmaxf(fmaxf(a0, a1), fmaxf(a2, a3));
    float sw0 = __expf(a0 - am), sw1 = __expf(a1 - am),
          sw2 = __expf(a2 - am), sw3 = __expf(a3 - am);
    float swinv = 1.f / (sw0 + sw1 + sw2 + sw3);
    sw0 *= swinv; sw1 *= swinv; sw2 *= swinv; sw3 *= swinv;

    // sequential coalesced reads: 4 view rows of this node (+ Wc1 rows)
    float4 z0 = *(const float4*)(Z + ((size_t)0 * N_ + node) * K_ + k0);
    float4 z1 = *(const float4*)(Z + ((size_t)1 * N_ + node) * K_ + k0);
    float4 z2 = *(const float4*)(Z + ((size_t)2 * N_ + node) * K_ + k0);
    float4 z3 = *(const float4*)(Z + ((size_t)3 * N_ + node) * K_ + k0);
    float4 w0 = *(const float4*)(Wc1 + 0 * K_ + k0);
    float4 w1 = *(const float4*)(Wc1 + 1 * K_ + k0);
    float4 w2 = *(const float4*)(Wc1 + 2 * K_ + k0);
    float4 w3 = *(const float4*)(Wc1 + 3 * K_ + k0);
    float4 c2 = *(const float4*)(Wc2 + k0);
    float4 cb = *(const float4*)(bc2h + k0);

    float4 zs;
    zs.x = z0.x + z1.x + z2.x + z3.x;
    zs.y = z0.y + z1.y + z2.y + z3.y;
    zs.z = z0.z + z1.z + z2.z + z3.z;
    zs.w = z0.w + z1.w + z2.w + z3.w;

    float dp = z0.x*w0.x + z0.y*w0.y + z0.z*w0.z + z0.w*w0.w
             + z1.x*w1.x + z1.y*w1.y + z1.z*w1.z + z1.w*w1.w
             + z2.x*w2.x + z2.y*w2.y + z2.z*w2.z + z2.w*w2.w
             + z3.x*w3.x + z3.y*w3.y + z3.z*w3.z + z3.w*w3.w;
#pragma unroll
    for (int off = 16; off >= 1; off >>= 1) dp += __shfl_xor(dp, off, 64);

    float a = lrelu(dp + bc1v);

    float l0 = fmaf(a, c2.x, cb.x), l1 = fmaf(a, c2.y, cb.y);
    float l2 = fmaf(a, c2.z, cb.z), l3 = fmaf(a, c2.w, cb.w);
    float m = fmaxf(fmaxf(l0, l1), fmaxf(l2, l3));
#pragma unroll
    for (int off = 16; off >= 1; off >>= 1) m = fmaxf(m, __shfl_xor(m, off, 64));
    float e0 = __expf(l0 - m), e1 = __expf(l1 - m),
          e2 = __expf(l2 - m), e3 = __expf(l3 - m);
    float s = e0 + e1 + e2 + e3;
#pragma unroll
    for (int off = 16; off >= 1; off >>= 1) s += __shfl_xor(s, off, 64);
    float inv = 1.f / s;

    float o0v = 0.5f * (zs.x * (e0 * inv) + (sw0*z0.x + sw1*z1.x + sw2*z2.x + sw3*z3.x));
    float o1v = 0.5f * (zs.y * (e1 * inv) + (sw0*z0.y + sw1*z1.y + sw2*z2.y + sw3*z3.y));
    float o2v = 0.5f * (zs.z * (e2 * inv) + (sw0*z0.z + sw1*z1.z + sw2*z2.z + sw3*z3.z));
    float o3v = 0.5f * (zs.w * (e3 * inv) + (sw0*z0.w + sw1*z1.w + sw2*z2.w + sw3*z3.w));

    ushort4 p;
    p.x = f2bf(o0v); p.y = f2bf(o1v); p.z = f2bf(o2v); p.w = f2bf(o3v);
    *(ushort4*)(dst + (size_t)node * K_ + k0) = p;
}

// ---------------------------------------------------------------------------
// Kernel 2: MFMA decoder, LDS-staged weights. 128 rows/block, 4 waves.
// R7 vs R6: W0T is staged into LDS in 2 halves (34KB buffer) so B-fragments
// come from ds_read instead of per-wave scattered global loads (the R6
// bottleneck: ~4k 64B txns/block through L1). Layer-1 is interleaved through
// a small per-wave scratch (o0's 35KB LDS tile eliminated). W1T (16KB) stays
// global -> L1-resident. LDS total 45KB -> 3 blocks/CU.
// ---------------------------------------------------------------------------
__global__ __launch_bounds__(256, 3)
void decoder_kernel(const unsigned short* __restrict__ Xemb,
                    const unsigned short* __restrict__ Yemb,
                    const unsigned short* __restrict__ W0img,
                    const unsigned short* __restrict__ W1T,
                    const float* __restrict__ b0, const float* __restrict__ b1,
                    const float* __restrict__ W2, const float* __restrict__ b2,
                    const int* __restrict__ idx0, const int* __restrict__ idx1,
                    float* __restrict__ out, int Btot)
{
    __shared__ unsigned short Wlds[HALF_ELEMS];          // 34816 B
    __shared__ unsigned short scr[4][32 * SCR_STRIDE];   // 4 x 2560 B

    const int wave = threadIdx.x >> 6;
    const int lane = threadIdx.x & 63;
    const int lx   = lane & 15;     // row (A) / col (B/C) index inside tile
    const int lk   = lane >> 4;     // k-group: k = lk*8 .. +7
    const int rowBase = blockIdx.x * 128 + wave * 32;
    unsigned short* myscr = scr[wave];

    int r0 = rowBase + lx;       if (r0 >= Btot) r0 = Btot - 1;
    int r1 = rowBase + 16 + lx;  if (r1 >= Btot) r1 = Btot - 1;
    const unsigned short* xb0 = Xemb + (size_t)idx0[r0] * K_ + lk * 8;
    const unsigned short* xb1 = Xemb + (size_t)idx0[r1] * K_ + lk * 8;
    const unsigned short* yb0 = Yemb + (size_t)idx1[r0] * K_ + lk * 8;
    const unsigned short* yb1 = Yemb + (size_t)idx1[r1] * K_ + lk * 8;

    // hoisted scalars
    float b0v[8], b1v[4], w2v[4];
#pragma unroll
    for (int n = 0; n < 8; ++n) b0v[n] = b0[n * 16 + lx];
#pragma unroll
    for (int n = 0; n < 4; ++n) { b1v[n] = b1[n * 16 + lx]; w2v[n] = W2[n * 16 + lx]; }
    const float b2v = b2[0];

    // A prefetch: all 16 fragments (cols 0..127 = X, 128..255 = Y), issued
    // before staging so the gather latency hides under the LDS fill.
    short8v A0[8], A1[8];
#pragma unroll
    for (int kk = 0; kk < 4; ++kk) {
        A0[kk]     = *(const short8v*)(xb0 + kk * 32);
        A1[kk]     = *(const short8v*)(xb1 + kk * 32);
        A0[kk + 4] = *(const short8v*)(yb0 + kk * 32);
        A1[kk + 4] = *(const short8v*)(yb1 + kk * 32);
    }

    f32x4 acc1[2][4];
#pragma unroll
    for (int m = 0; m < 2; ++m)
#pragma unroll
        for (int n = 0; n < 4; ++n) acc1[m][n] = (f32x4)0.f;

#pragma unroll
    for (int h = 0; h < 2; ++h) {
        // ---- stage half h of the W0 image: rows [h*64, h*64+64) ----
        {
            const unsigned short* src = W0img + h * HALF_ELEMS;
#pragma unroll
            for (int it = 0; it < 9; ++it) {
                int e = it * 2048 + threadIdx.x * 8;
                if (e < HALF_ELEMS)
                    *(short8v*)&Wlds[e] = *(const short8v*)&src[e];
            }
        }
        __syncthreads();   // fill visible to all waves

        // ---- 4 col-tiles of layer 0 + interleaved layer 1 ----
        for (int nl = 0; nl < 4; ++nl) {
            const int n = h * 4 + nl;
            const unsigned short* wb = Wlds + (nl * 16 + lx) * LDSTRIDE + lk * 8;

            f32x4 accn[2];
            accn[0] = (f32x4)0.f; accn[1] = (f32x4)0.f;
#pragma unroll
            for (int kk = 0; kk < 8; ++kk) {
                short8v Bv = *(const short8v*)(wb + kk * 32);
                accn[0] = __builtin_amdgcn_mfma_f32_16x16x32_bf16(A0[kk], Bv, accn[0], 0, 0, 0);
                accn[1] = __builtin_amdgcn_mfma_f32_16x16x32_bf16(A1[kk], Bv, accn[1], 0, 0, 0);
            }

            // epilogue: +b0, lrelu, bf16 -> per-wave scratch (transpose)
            // C map: col = n*16+lx, row = m*16 + lk*4 + r
            const int ncol = (n & 1) * 16 + lx;
#pragma unroll
            for (int m = 0; m < 2; ++m)
#pragma unroll
                for (int r = 0; r < 4; ++r) {
                    float v = lrelu(accn[m][r] + b0v[n]);
                    myscr[(m * 16 + lk * 4 + r) * SCR_STRIDE + ncol] = f2bf(v);
                }

            if (n & 1) {   // 32-col chunk complete -> one layer-1 K-step
                const int kk1 = n >> 1;
                short8v La0 = *(const short8v*)&myscr[lx * SCR_STRIDE + lk * 8];
                short8v La1 = *(const short8v*)&myscr[(16 + lx) * SCR_STRIDE + lk * 8];
#pragma unroll
                for (int n1 = 0; n1 < 4; ++n1) {
                    short8v Bv1 = *(const short8v*)(W1T + (size_t)(n1 * 16 + lx) * 128 + kk1 * 32 + lk * 8);
                    acc1[0][n1] = __builtin_amdgcn_mfma_f32_16x16x32_bf16(La0, Bv1, acc1[0][n1], 0, 0, 0);
                    acc1[1][n1] = __builtin_amdgcn_mfma_f32_16x16x32_bf16(La1, Bv1, acc1[1][n1], 0, 0, 0);
                }
            }
        }
        __syncthreads();   // all reads of this half done before restage
    }

    // ---------------- layer 2: o1[32,64] . W2[64] + b2, sigmoid ----------------
    {
        float t[2][4];
#pragma unroll
        for (int m = 0; m < 2; ++m)
#pragma unroll
            for (int r = 0; r < 4; ++r) t[m][r] = 0.f;
#pragma unroll
        for (int m = 0; m < 2; ++m)
#pragma unroll
            for (int n = 0; n < 4; ++n)
#pragma unroll
                for (int r = 0; r < 4; ++r) {
                    float v = lrelu(acc1[m][n][r] + b1v[n]);
                    t[m][r] = fmaf(v, w2v[n], t[m][r]);
                }
#pragma unroll
        for (int off = 8; off >= 1; off >>= 1)
#pragma unroll
            for (int m = 0; m < 2; ++m)
#pragma unroll
                for (int r = 0; r < 4; ++r)
                    t[m][r] += __shfl_xor(t[m][r], off, 64);
        if (lx == 0) {
#pragma unroll
            for (int m = 0; m < 2; ++m)
#pragma unroll
                for (int r = 0; r < 4; ++r) {
                    int row = rowBase + m * 16 + lk * 4 + r;
                    if (row < Btot)
                        out[row] = 1.f / (1.f + __expf(-(t[m][r] + b2v)));
                }
        }
    }
}

// ---------------------------------------------------------------------------
// Fallback (round-1 fused kernel) if ws is too small for the split pipeline.
// ---------------------------------------------------------------------------
#define PPB  32
#define NT   256
#define FSTR 260
#define O0STR 132
#define O1STR 68

__device__ __forceinline__ void embed_side_f(
    const float* __restrict__ Z, int idx,
    const float* __restrict__ Wc1, float bc1v,
    const float* __restrict__ Wc2, const float* __restrict__ bc2,
    float sw0, float sw1, float sw2, float sw3,
    int lane, float* dst)
{
    const int k0 = 2 * lane;
    const float* base = Z + (size_t)idx * K_ + k0;
    float2 z0 = *(const float2*)(base + (size_t)0 * N_ * K_);
    float2 z1 = *(const float2*)(base + (size_t)1 * N_ * K_);
    float2 z2 = *(const float2*)(base + (size_t)2 * N_ * K_);
    float2 z3 = *(const float2*)(base + (size_t)3 * N_ * K_);
    float zs0 = z0.x + z1.x + z2.x + z3.x;
    float zs1 = z0.y + z1.y + z2.y + z3.y;
    float2 w0 = *(const float2*)(Wc1 + 0 * K_ + k0);
    float2 w1 = *(const float2*)(Wc1 + 1 * K_ + k0);
    float2 w2 = *(const float2*)(Wc1 + 2 * K_ + k0);
    float2 w3 = *(const float2*)(Wc1 + 3 * K_ + k0);
    float dp = z0.x*w0.x + z0.y*w0.y + z1.x*w1.x + z1.y*w1.y
             + z2.x*w2.x + z2.y*w2.y + z3.x*w3.x + z3.y*w3.y;
#pragma unroll
    for (int off = 32; off >= 1; off >>= 1) dp += __shfl_xor(dp, off, 64);
    float a = lrelu(dp + bc1v);
    float2 c2 = *(const float2*)(Wc2 + k0);
    float2 cb = *(const float2*)(bc2 + k0);
    float l0 = fmaf(a, c2.x, cb.x), l1 = fmaf(a, c2.y, cb.y);
    float m = fmaxf(l0, l1);
#pragma unroll
    for (int off = 32; off >= 1; off >>= 1) m = fmaxf(m, __shfl_xor(m, off, 64));
    float e0 = __expf(l0 - m), e1 = __expf(l1 - m);
    float s = e0 + e1;
#pragma unroll
    for (int off = 32; off >= 1; off >>= 1) s += __shfl_xor(s, off, 64);
    float inv = 1.f / s;
    float e8a = sw0*z0.x + sw1*z1.x + sw2*z2.x + sw3*z3.x;
    float e8b = sw0*z0.y + sw1*z1.y + sw2*z2.y + sw3*z3.y;
    *(float2*)(dst + k0) = make_float2(0.5f*(zs0*(e0*inv)+e8a), 0.5f*(zs1*(e1*inv)+e8b));
}

__global__ __launch_bounds__(NT)
void mf_fused(const float* __restrict__ X, const float* __restrict__ Y,
              const float* __restrict__ x_att, const float* __restrict__ y_att,
              const float* __restrict__ WcX1, const float* __restrict__ bcX1,
              const float* __restrict__ WcX2, const float* __restrict__ bcX2,
              const float* __restrict__ WcY1, const float* __restrict__ bcY1,
              const float* __restrict__ WcY2, const float* __restrict__ bcY2,
              const float* __restrict__ W0, const float* __restrict__ b0,
              const float* __restrict__ W1, const float* __restrict__ b1,
              const float* __restrict__ W2, const float* __restrict__ b2,
              const int* __restrict__ idx0, const int* __restrict__ idx1,
              float* __restrict__ out, int Btot)
{
    __shared__ float pool[PPB * FSTR];
    float* feat = pool;
    const int tid  = threadIdx.x;
    const int lane = tid & 63;
    const int wave = tid >> 6;
    float swx0, swx1, swx2, swx3, swy0, swy1, swy2, swy3;
    {
        float a0 = x_att[0], a1 = x_att[1], a2 = x_att[2], a3 = x_att[3];
        float m = fmaxf(fmaxf(a0, a1), fmaxf(a2, a3));
        float e0 = __expf(a0-m), e1 = __expf(a1-m), e2 = __expf(a2-m), e3 = __expf(a3-m);
        float inv = 1.f / (e0+e1+e2+e3);
        swx0=e0*inv; swx1=e1*inv; swx2=e2*inv; swx3=e3*inv;
        float b0v=y_att[0], b1v=y_att[1], b2v=y_att[2], b3v=y_att[3];
        float my = fmaxf(fmaxf(b0v,b1v), fmaxf(b2v,b3v));
        float f0=__expf(b0v-my), f1=__expf(b1v-my), f2=__expf(b2v-my), f3=__expf(b3v-my);
        float invy = 1.f/(f0+f1+f2+f3);
        swy0=f0*invy; swy1=f1*invy; swy2=f2*invy; swy3=f3*invy;
    }
    const float bcX1v = bcX1[0], bcY1v = bcY1[0];
    const long pair_base = (long)blockIdx.x * PPB;
    for (int pp = 0; pp < PPB/4; ++pp) {
        const int p_local = wave * (PPB/4) + pp;
        const long pair = pair_base + p_local;
        if (pair < Btot) {
            embed_side_f(X, idx0[pair], WcX1, bcX1v, WcX2, bcX2, swx0,swx1,swx2,swx3, lane, feat + p_local*FSTR);
            embed_side_f(Y, idx1[pair], WcY1, bcY1v, WcY2, bcY2, swy0,swy1,swy2,swy3, lane, feat + p_local*FSTR + K_);
        }
    }
    __syncthreads();
    const int jg = tid & 15, pg = tid >> 4;
    float acc[2][8];
#pragma unroll
    for (int p=0;p<2;++p)
#pragma unroll
        for (int j=0;j<8;++j) acc[p][j]=0.f;
    const float* frow0 = feat + (pg*2+0)*FSTR;
    const float* frow1 = feat + (pg*2+1)*FSTR;
    for (int i = 0; i < 2*K_; i += 4) {
        float fav[4], fbv[4];
        *(float4*)fav = *(const float4*)(frow0+i);
        *(float4*)fbv = *(const float4*)(frow1+i);
#pragma unroll
        for (int u=0;u<4;++u) {
            float wv[8];
            *(float4*)(wv)   = *(const float4*)(W0 + (i+u)*K_ + jg*8);
            *(float4*)(wv+4) = *(const float4*)(W0 + (i+u)*K_ + jg*8 + 4);
#pragma unroll
            for (int j=0;j<8;++j) {
                acc[0][j] = fmaf(fav[u], wv[j], acc[0][j]);
                acc[1][j] = fmaf(fbv[u], wv[j], acc[1][j]);
            }
        }
    }
    __syncthreads();
    float* o0 = pool;
    {
        float bv[8];
        *(float4*)bv     = *(const float4*)(b0 + jg*8);
        *(float4*)(bv+4) = *(const float4*)(b0 + jg*8 + 4);
#pragma unroll
        for (int p=0;p<2;++p) {
            float v[8];
#pragma unroll
            for (int j=0;j<8;++j) v[j] = lrelu(acc[p][j] + bv[j]);
            *(float4*)(o0 + (pg*2+p)*O0STR + jg*8)     = *(float4*)v;
            *(float4*)(o0 + (pg*2+p)*O0STR + jg*8 + 4) = *(float4*)(v+4);
        }
    }
    __syncthreads();
    float acc1[2][4];
#pragma unroll
    for (int p=0;p<2;++p)
#pragma unroll
        for (int j=0;j<4;++j) acc1[p][j]=0.f;
    const float* r0 = o0 + (pg*2+0)*O0STR;
    const float* r1 = o0 + (pg*2+1)*O0STR;
    for (int i = 0; i < K_; i += 4) {
        float fav[4], fbv[4];
        *(float4*)fav = *(const float4*)(r0+i);
        *(float4*)fbv = *(const float4*)(r1+i);
#pragma unroll
        for (int u=0;u<4;++u) {
            float wv[4];
            *(float4*)wv = *(const float4*)(W1 + (i+u)*(K_/2) + jg*4);
#pragma unroll
            for (int j=0;j<4;++j) {
                acc1[0][j] = fmaf(fav[u], wv[j], acc1[0][j]);
                acc1[1][j] = fmaf(fbv[u], wv[j], acc1[1][j]);
            }
        }
    }
    float* o1 = pool + PPB*O0STR;
    {
        float bv[4];
        *(float4*)bv = *(const float4*)(b1 + jg*4);
#pragma unroll
        for (int p=0;p<2;++p) {
            float v[4];
#pragma unroll
            for (int j=0;j<4;++j) v[j] = lrelu(acc1[p][j] + bv[j]);
            *(float4*)(o1 + (pg*2+p)*O1STR + jg*4) = *(float4*)v;
        }
    }
    __syncthreads();
    {
        const int p = tid >> 3, part = tid & 7;
        const float* r = o1 + p*O1STR + part*8;
        float rv[8], wv[8];
        *(float4*)rv     = *(const float4*)(r);
        *(float4*)(rv+4) = *(const float4*)(r+4);
        *(float4*)wv     = *(const float4*)(W2 + part*8);
        *(float4*)(wv+4) = *(const float4*)(W2 + part*8 + 4);
        float d = 0.f;
#pragma unroll
        for (int j=0;j<8;++j) d = fmaf(rv[j], wv[j], d);
        d += __shfl_xor(d, 1, 64);
        d += __shfl_xor(d, 2, 64);
        d += __shfl_xor(d, 4, 64);
        if (part == 0) {
            const long pair = pair_base + p;
            if (pair < Btot) out[pair] = 1.f / (1.f + __expf(-(d + b2[0])));
        }
    }
}

// ---------------------------------------------------------------------------
extern "C" void kernel_launch(void* const* d_in, const int* in_sizes, int n_in,
                              void* d_out, int out_size, void* d_ws, size_t ws_size,
                              hipStream_t stream) {
    const float* X    = (const float*)d_in[0];
    const float* Y    = (const float*)d_in[1];
    const float* xatt = (const float*)d_in[2];
    const float* yatt = (const float*)d_in[3];
    const float* WcX1 = (const float*)d_in[4];
    const float* bcX1 = (const float*)d_in[5];
    const float* WcX2 = (const float*)d_in[6];
    const float* bcX2 = (const float*)d_in[7];
    const float* WcY1 = (const float*)d_in[8];
    const float* bcY1 = (const float*)d_in[9];
    const float* WcY2 = (const float*)d_in[10];
    const float* bcY2 = (const float*)d_in[11];
    const float* W0   = (const float*)d_in[12];
    const float* b0   = (const float*)d_in[13];
    const float* W1   = (const float*)d_in[14];
    const float* b1   = (const float*)d_in[15];
    const float* W2   = (const float*)d_in[16];
    const float* b2   = (const float*)d_in[17];
    const int* idx0   = (const int*)d_in[18];
    const int* idx1   = (const int*)d_in[19];
    float* out        = (float*)d_out;

    const int Btot = in_sizes[18];
    const int dblocks = (Btot + 127) / 128;
    // ws layout: [0,128K) W0img | [128K,160K) W1T | [1M,5M) Xemb | [5M,9M) Yemb
    const size_t need = (9u << 20);

    if (ws_size >= need) {
        unsigned short* W0img = (unsigned short*)d_ws;
        unsigned short* W1T   = (unsigned short*)((char*)d_ws + 131072);
        unsigned short* Xemb  = (unsigned short*)((char*)d_ws + (1u << 20));
        unsigned short* Yemb  = (unsigned short*)((char*)d_ws + (5u << 20));

        embed_convert<<<CONV_BLOCKS + N_ / 4, 256, 0, stream>>>(
            X, Y, xatt, yatt, WcX1, bcX1, WcX2, bcX2,
            WcY1, bcY1, WcY2, bcY2, W0, W1, W0img, W1T, Xemb, Yemb);
        decoder_kernel<<<dblocks, 256, 0, stream>>>(
            Xemb, Yemb, W0img, W1T, b0, b1, W2, b2, idx0, idx1, out, Btot);
    } else {
        mf_fused<<<(Btot + PPB - 1) / PPB, NT, 0, stream>>>(
            X, Y, xatt, yatt, WcX1, bcX1, WcX2, bcX2,
            WcY1, bcY1, WcY2, bcY2, W0, b0, W1, b1, W2, b2,
            idx0, idx1, out, Btot);
    }
}